// Round 3
// baseline (310.058 us; speedup 1.0000x reference)
//
#include <hip/hip_runtime.h>
#include <math.h>

typedef short s16x8 __attribute__((ext_vector_type(8)));
typedef short s16x4 __attribute__((ext_vector_type(4)));
typedef float f32x4 __attribute__((ext_vector_type(4)));

#define MFMA(a, b, c)    __builtin_amdgcn_mfma_f32_16x16x32_bf16(a, b, c, 0, 0, 0)
#define MFMA16(a, b, c)  __builtin_amdgcn_mfma_f32_16x16x16bf16_1k(a, b, c, 0, 0, 0)

__device__ __forceinline__ float b2f(ushort u) {
    union { unsigned int i; float f; } v; v.i = ((unsigned int)u) << 16; return v.f;
}
__device__ __forceinline__ ushort f2b(float f) {
    union { float f; unsigned int i; } v; v.f = f;
    unsigned int r = v.i + 0x7fffu + ((v.i >> 16) & 1u);
    return (ushort)(r >> 16);
}
__device__ __forceinline__ float gelu_tanh(float v) {
    float u = 0.7978845608f * (v + 0.044715f * v * v * v);
    float e = __expf(-2.f * fabsf(u));
    float t = (1.f - e) / (1.f + e);            // tanh(|u|)
    t = (u < 0.f) ? -t : t;
    return 0.5f * v * (1.f + t);
}

// ---------------------------------------------------------------------------
// K0: all prep. blocks [0,192): qkv_w->wq; [192,256): proj_w->wp;
// [256,768): fc1/fc2->wf; [768,832): bias+mask table bm[cls][head][128][128].
// ---------------------------------------------------------------------------
__global__ __launch_bounds__(256) void k0_prep(
    const float* __restrict__ qkv_w, const float* __restrict__ proj_w,
    const float* __restrict__ fc1_w, const float* __restrict__ fc2_w,
    const float* __restrict__ rpb, ushort* __restrict__ wq,
    ushort* __restrict__ wp, ushort* __restrict__ wf, ushort* __restrict__ bm)
{
    int bid = blockIdx.x, tid = threadIdx.x;
    if (bid < 192) { int idx = bid * 256 + tid; wq[idx] = f2b(qkv_w[idx]); return; }
    if (bid < 256) { int idx = (bid - 192) * 256 + tid; wp[idx] = f2b(proj_w[idx]); return; }
    if (bid < 768) {
        int idx = (bid - 256) * 256 + tid;
        wf[idx] = f2b(idx < 65536 ? fc1_w[idx] : fc2_w[idx - 65536]);
        return;
    }
    int bi = bid - 768;                             // [0,64) = cls*8+head
    int cls = bi >> 3, head = bi & 7;
    int ed = (cls >> 2) & 1, eh = (cls >> 1) & 1, ew = cls & 1;
    int j = tid & 127;
    int tdj = j >> 6, thj = (j >> 3) & 7, twj = j & 7;
    int regj = (ed ? (tdj + 1) : 0) * 9
             + (eh ? ((thj < 4) ? 1 : 2) : 0) * 3
             + (ew ? ((twj < 4) ? 1 : 2) : 0);
    ushort* bmp = bm + (long)bi * 16384;
    for (int ii = 0; ii < 64; ++ii) {
        int i = (tid >> 7) * 64 + ii;
        int tdi = i >> 6, thi = (i >> 3) & 7, twi = i & 7;
        int regi = (ed ? (tdi + 1) : 0) * 9
                 + (eh ? ((thi < 4) ? 1 : 2) : 0) * 3
                 + (ew ? ((twi < 4) ? 1 : 2) : 0);
        int rpi = (tdi - tdj + 1) * 225 + (thi - thj + 7) * 15 + (twi - twj + 7);
        float v = rpb[rpi * 8 + head] + ((regi != regj) ? -100.f : 0.f);
        bmp[i * 128 + j] = f2b(v);
    }
}

// ---------------------------------------------------------------------------
// K2: fused LN1 + cyclic-shift + window gather + QKV GEMM.
// Output WINDOW-major: qkv[wi][mat][head][token][16] (strides 49152/16384/2048/16).
// ---------------------------------------------------------------------------
__global__ __launch_bounds__(256) void k2_qkv(
    const float* __restrict__ x, const float* __restrict__ g,
    const float* __restrict__ be, const ushort* __restrict__ wq,
    const float* __restrict__ qkv_b, ushort* __restrict__ qkv)
{
    __shared__ __align__(16) ushort As[128][136];
    int tid = threadIdx.x;
    int m0 = blockIdx.x * 128;
    {   // LN + shift + gather -> As (2 threads per row)
        int row = tid >> 1, half = tid & 1;
        int tk = m0 + row;
        int wi = tk >> 7, t = tk & 127;
        int b = wi >> 8, wd = (wi >> 6) & 3, wh = (wi >> 3) & 7, ww = wi & 7;
        int td = t >> 6, th = (t >> 3) & 7, tw = t & 7;
        int d = (wd * 2 + td + 1) & 7;
        int h = (wh * 8 + th + 4) & 63;
        int w = (ww * 8 + tw + 4) & 63;
        long src = (((long)((b * 8 + d) * 64 + h)) * 64 + w) * 128 + half * 64;
        float vals[64];
        float s = 0.f, q = 0.f;
        #pragma unroll
        for (int i = 0; i < 16; ++i) {
            float4 u = *(const float4*)&x[src + i * 4];
            vals[i * 4 + 0] = u.x; vals[i * 4 + 1] = u.y;
            vals[i * 4 + 2] = u.z; vals[i * 4 + 3] = u.w;
            s += u.x + u.y + u.z + u.w;
            q += u.x * u.x + u.y * u.y + u.z * u.z + u.w * u.w;
        }
        s += __shfl_xor(s, 1);
        q += __shfl_xor(q, 1);
        float mean = s * (1.f / 128.f);
        float rstd = rsqrtf(q * (1.f / 128.f) - mean * mean + 1e-5f);
        #pragma unroll
        for (int i = 0; i < 8; ++i) {
            ushort pk[8];
            #pragma unroll
            for (int jj = 0; jj < 8; ++jj) {
                int c = half * 64 + i * 8 + jj;
                pk[jj] = f2b((vals[i * 8 + jj] - mean) * rstd * g[c] + be[c]);
            }
            *(uint4*)&As[row][half * 64 + i * 8] = *(uint4*)pk;
        }
    }
    __syncthreads();
    int wv = tid >> 6, lane = tid & 63, li = lane & 15, quad = lane >> 4;
    int wm = wv >> 1, wn = wv & 1;
    long wibase = (long)(m0 >> 7) * 49152;
    for (int nb = 0; nb < 3; ++nb) {
        f32x4 acc[4][4] = {};
        for (int s = 0; s < 4; ++s) {
            s16x8 a[4], bw[4];
            #pragma unroll
            for (int mi = 0; mi < 4; ++mi)
                a[mi] = *(const s16x8*)&As[wm * 64 + mi * 16 + li][s * 32 + quad * 8];
            #pragma unroll
            for (int ni = 0; ni < 4; ++ni)
                bw[ni] = *(const s16x8*)&wq[(long)(nb * 128 + wn * 64 + ni * 16 + li) * 128
                                            + s * 32 + quad * 8];
            #pragma unroll
            for (int mi = 0; mi < 4; ++mi)
                #pragma unroll
                for (int ni = 0; ni < 4; ++ni)
                    acc[mi][ni] = MFMA(a[mi], bw[ni], acc[mi][ni]);
        }
        #pragma unroll
        for (int mi = 0; mi < 4; ++mi)
            #pragma unroll
            for (int ni = 0; ni < 4; ++ni) {
                int gcol = nb * 128 + wn * 64 + ni * 16 + li;
                int mat = gcol >> 7, hd = (gcol >> 4) & 7;
                float bias = qkv_b[gcol];
                float scale = (mat == 0) ? 0.25f : 1.f;   // SCALE = 16^-0.5
                long base2 = wibase + mat * 16384 + hd * 2048 + li;
                #pragma unroll
                for (int r = 0; r < 4; ++r) {
                    int trow = wm * 64 + mi * 16 + quad * 4 + r;
                    qkv[base2 + trow * 16] = f2b((acc[mi][ni][r] + bias) * scale);
                }
            }
    }
}

// ---------------------------------------------------------------------------
// K3 (R3 rewrite): 1 wave per block, 32 q-rows, grid = 512 windows x 4 quarters.
// Swapped QK^T: S^T = mfma16(K, Q) puts P[i=li][j=quad*4+r] in exactly the
// A-fragment layout PV needs -> P never touches LDS. Q/K fragments load
// directly from global (own rows only). Softmax: no row-max (S bounded ~1),
// sum via 2 shfl_xor, 1/sum applied to PV OUTPUT (linearity). Only V is
// LDS-staged (transposed, 4.4KB). O written per-head HEAD-MAJOR over the
// q-slot just consumed: qkv[wbase + h*2048 + tok*16 + d] (own rows only ->
// no cross-head/cross-block aliasing).
// ---------------------------------------------------------------------------
__global__ __launch_bounds__(64) void k3_attn(
    ushort* __restrict__ qkv, const ushort* __restrict__ bm)
{
    __shared__ __align__(16) ushort vt[16][136];
    int b = blockIdx.x;
    int wi = b >> 2, qq = b & 3;
    int wd = (wi >> 6) & 3, wh = (wi >> 3) & 7, ww = wi & 7;
    int cls = ((wd == 3) << 2) | ((wh == 7) << 1) | (ww == 7);
    int lane = threadIdx.x;
    int li = lane & 15, quad = lane >> 4;
    long wbase = (long)wi * 49152;
    int row0 = qq * 32;
    for (int h = 0; h < 8; ++h) {
        __syncthreads();   // (1-wave: compiles to waitcnt; keeps vt WAR safe)
        #pragma unroll
        for (int t2 = 0; t2 < 2; ++t2) {
            int tok = t2 * 64 + lane;
            const ushort* vp = &qkv[wbase + 32768 + h * 2048 + tok * 16];
            uint4 v0 = *(const uint4*)vp;
            uint4 v1 = *(const uint4*)(vp + 8);
            const ushort* p0 = (const ushort*)&v0;
            const ushort* p1 = (const ushort*)&v1;
            #pragma unroll
            for (int j = 0; j < 8; ++j) { vt[j][tok] = p0[j]; vt[8 + j][tok] = p1[j]; }
        }
        __syncthreads();
        s16x4 qf0 = *(const s16x4*)&qkv[wbase + h * 2048 + (row0 + li) * 16 + quad * 4];
        s16x4 qf1 = *(const s16x4*)&qkv[wbase + h * 2048 + (row0 + 16 + li) * 16 + quad * 4];
        long bmb = (long)(cls * 8 + h) * 16384;
        float ps0 = 0.f, ps1 = 0.f;
        uint pa0[8][2], pa1[8][2];
        #pragma unroll
        for (int mi = 0; mi < 8; ++mi) {
            s16x4 kf = *(const s16x4*)&qkv[wbase + 16384 + h * 2048 + (mi * 16 + li) * 16 + quad * 4];
            f32x4 z = {0.f, 0.f, 0.f, 0.f};
            f32x4 s0 = MFMA16(kf, qf0, z);
            f32x4 s1 = MFMA16(kf, qf1, z);
            s16x4 b0 = *(const s16x4*)&bm[bmb + (row0 + li) * 128 + mi * 16 + quad * 4];
            s16x4 b1 = *(const s16x4*)&bm[bmb + (row0 + 16 + li) * 128 + mi * 16 + quad * 4];
            float e0 = __expf(s0[0] + b2f((ushort)b0[0]));
            float e1 = __expf(s0[1] + b2f((ushort)b0[1]));
            float e2 = __expf(s0[2] + b2f((ushort)b0[2]));
            float e3 = __expf(s0[3] + b2f((ushort)b0[3]));
            ps0 += (e0 + e1) + (e2 + e3);
            pa0[mi][0] = (uint)f2b(e0) | ((uint)f2b(e1) << 16);
            pa0[mi][1] = (uint)f2b(e2) | ((uint)f2b(e3) << 16);
            float f0 = __expf(s1[0] + b2f((ushort)b1[0]));
            float f1 = __expf(s1[1] + b2f((ushort)b1[1]));
            float f2 = __expf(s1[2] + b2f((ushort)b1[2]));
            float f3 = __expf(s1[3] + b2f((ushort)b1[3]));
            ps1 += (f0 + f1) + (f2 + f3);
            pa1[mi][0] = (uint)f2b(f0) | ((uint)f2b(f1) << 16);
            pa1[mi][1] = (uint)f2b(f2) | ((uint)f2b(f3) << 16);
        }
        ps0 += __shfl_xor(ps0, 16); ps0 += __shfl_xor(ps0, 32);
        ps1 += __shfl_xor(ps1, 16); ps1 += __shfl_xor(ps1, 32);
        float inv0 = 1.f / ps0, inv1 = 1.f / ps1;
        f32x4 pc0 = {0.f, 0.f, 0.f, 0.f}, pc1 = {0.f, 0.f, 0.f, 0.f};
        #pragma unroll
        for (int mi = 0; mi < 8; ++mi) {
            s16x4 vf = *(const s16x4*)&vt[li][mi * 16 + quad * 4];
            union { uint2 u; s16x4 v; } a0, a1;
            a0.u.x = pa0[mi][0]; a0.u.y = pa0[mi][1];
            a1.u.x = pa1[mi][0]; a1.u.y = pa1[mi][1];
            pc0 = MFMA16(a0.v, vf, pc0);
            pc1 = MFMA16(a1.v, vf, pc1);
        }
        #pragma unroll
        for (int r = 0; r < 4; ++r) {
            float oi0 = __shfl(inv0, quad * 4 + r);
            float oi1 = __shfl(inv1, quad * 4 + r);
            int i0 = row0 + quad * 4 + r;
            int i1 = row0 + 16 + quad * 4 + r;
            qkv[wbase + h * 2048 + (long)i0 * 16 + li] = f2b(pc0[r] * oi0);
            qkv[wbase + h * 2048 + (long)i1 * 16 + li] = f2b(pc1[r] * oi1);
        }
    }
}

// ---------------------------------------------------------------------------
// K45: fused proj GEMM + bias + residual + LN2 + FC1 + gelu + FC2 + residual
// + window-reverse/unshift scattered f32 store. 64-token tile, 1024 blocks.
// R3: ao now HEAD-MAJOR [wi][head][tok][16] (written by new k3 over q-slots);
// staging loop regathers it into As[tok][128ch]. Downstream unchanged.
// ---------------------------------------------------------------------------
__global__ __launch_bounds__(256) void k45(
    const ushort* __restrict__ ao, const ushort* __restrict__ wp,
    const float* __restrict__ proj_b, const float* __restrict__ x,
    const float* __restrict__ g2, const float* __restrict__ be2,
    const ushort* __restrict__ wf1, const float* __restrict__ fc1_b,
    const ushort* __restrict__ wf2, const float* __restrict__ fc2_b,
    float* __restrict__ out)
{
    __shared__ __align__(16) ushort As[64][132];    // ao tile, later xs (LN2 out)
    __shared__ __align__(16) ushort hs[64][132];    // gelu(h) chunk
    __shared__ float redS[2][64];
    __shared__ float redQ[2][64];
    int tid = threadIdx.x;
    int b = blockIdx.x;
    int wi = b >> 1, half64 = b & 1;
    int wd = (wi >> 6) & 3, wh = (wi >> 3) & 7, ww = wi & 7;
    int bb = wi >> 8;
    long aob = (long)wi * 49152;
    int tok0 = half64 * 64;
    #pragma unroll
    for (int i = 0; i < 4; ++i) {
        int slot = tid + i * 256;           // 0..1023
        int row = slot & 63, hsl = slot >> 6;   // hsl = head*2 + (d-half)
        *(uint4*)&As[row][hsl * 8] =
            *(const uint4*)&ao[aob + (hsl >> 1) * 2048 + (long)(tok0 + row) * 16 + (hsl & 1) * 8];
    }
    __syncthreads();
    int wv = tid >> 6, lane = tid & 63, li = lane & 15, quad = lane >> 4;
    int wm = wv >> 1, wn = wv & 1;
    f32x4 acc[2][4] = {};
    for (int s = 0; s < 4; ++s) {
        s16x8 a[2], bw[4];
        #pragma unroll
        for (int mi = 0; mi < 2; ++mi)
            a[mi] = *(const s16x8*)&As[wm * 32 + mi * 16 + li][s * 32 + quad * 8];
        #pragma unroll
        for (int ni = 0; ni < 4; ++ni)
            bw[ni] = *(const s16x8*)&wp[(long)(wn * 64 + ni * 16 + li) * 128 + s * 32 + quad * 8];
        #pragma unroll
        for (int mi = 0; mi < 2; ++mi)
            #pragma unroll
            for (int ni = 0; ni < 4; ++ni)
                acc[mi][ni] = MFMA(a[mi], bw[ni], acc[mi][ni]);
    }
    // epilogue: x1 = acc + proj_b + x (f32, in-place in acc); LN2 row partials
    int cols[4];
    #pragma unroll
    for (int ni = 0; ni < 4; ++ni) cols[ni] = wn * 64 + ni * 16 + li;
    {
        float pbv[4];
        #pragma unroll
        for (int ni = 0; ni < 4; ++ni) pbv[ni] = proj_b[cols[ni]];
        #pragma unroll
        for (int mi = 0; mi < 2; ++mi) {
            #pragma unroll
            for (int r = 0; r < 4; ++r) {
                int lrow = wm * 32 + mi * 16 + quad * 4 + r;
                int t = half64 * 64 + lrow;
                int td = t >> 6, th = (t >> 3) & 7, tw = t & 7;
                int d = (wd * 2 + td + 1) & 7, h = (wh * 8 + th + 4) & 63, w = (ww * 8 + tw + 4) & 63;
                long di = (((long)((bb * 8 + d) * 64 + h)) * 64 + w) * 128;
                float s_ = 0.f, q_ = 0.f;
                #pragma unroll
                for (int ni = 0; ni < 4; ++ni) {
                    float v = acc[mi][ni][r] + pbv[ni] + x[di + cols[ni]];
                    acc[mi][ni][r] = v;
                    s_ += v; q_ += v * v;
                }
                #pragma unroll
                for (int m = 1; m < 16; m <<= 1) {
                    s_ += __shfl_xor(s_, m);
                    q_ += __shfl_xor(q_, m);
                }
                if (li == 0) { redS[wn][lrow] = s_; redQ[wn][lrow] = q_; }
            }
        }
    }
    __syncthreads();
    // LN2 normalize -> As (xs); pack x1 -> bf16x2 regs
    {
        float g2v[4], be2v[4];
        #pragma unroll
        for (int ni = 0; ni < 4; ++ni) { g2v[ni] = g2[cols[ni]]; be2v[ni] = be2[cols[ni]]; }
        #pragma unroll
        for (int mi = 0; mi < 2; ++mi) {
            #pragma unroll
            for (int r = 0; r < 4; ++r) {
                int lrow = wm * 32 + mi * 16 + quad * 4 + r;
                float tS = redS[0][lrow] + redS[1][lrow];
                float tQ = redQ[0][lrow] + redQ[1][lrow];
                float mean = tS * (1.f / 128.f);
                float rstd = rsqrtf(tQ * (1.f / 128.f) - mean * mean + 1e-5f);
                #pragma unroll
                for (int ni = 0; ni < 4; ++ni)
                    As[lrow][cols[ni]] = f2b((acc[mi][ni][r] - mean) * rstd * g2v[ni] + be2v[ni]);
            }
        }
    }
    uint x1p[2][4][2];
    #pragma unroll
    for (int mi = 0; mi < 2; ++mi)
        #pragma unroll
        for (int ni = 0; ni < 4; ++ni)
            #pragma unroll
            for (int rr = 0; rr < 2; ++rr)
                x1p[mi][ni][rr] = (unsigned int)f2b(acc[mi][ni][2 * rr])
                                | ((unsigned int)f2b(acc[mi][ni][2 * rr + 1]) << 16);
    __syncthreads();
    f32x4 yacc[2][4] = {};
    for (int hc = 0; hc < 4; ++hc) {
        f32x4 hacc[2][4] = {};
        #pragma unroll
        for (int kk = 0; kk < 4; ++kk) {
            s16x8 a[2], bw[4];
            #pragma unroll
            for (int mi = 0; mi < 2; ++mi)
                a[mi] = *(const s16x8*)&As[wm * 32 + mi * 16 + li][kk * 32 + quad * 8];
            #pragma unroll
            for (int ni = 0; ni < 4; ++ni)
                bw[ni] = *(const s16x8*)&wf1[(long)(hc * 128 + wn * 64 + ni * 16 + li) * 128
                                             + kk * 32 + quad * 8];
            #pragma unroll
            for (int mi = 0; mi < 2; ++mi)
                #pragma unroll
                for (int ni = 0; ni < 4; ++ni)
                    hacc[mi][ni] = MFMA(a[mi], bw[ni], hacc[mi][ni]);
        }
        #pragma unroll
        for (int mi = 0; mi < 2; ++mi)
            #pragma unroll
            for (int ni = 0; ni < 4; ++ni) {
                int col = wn * 64 + ni * 16 + li;
                float bbv = fc1_b[hc * 128 + col];
                #pragma unroll
                for (int r = 0; r < 4; ++r) {
                    int row = wm * 32 + mi * 16 + quad * 4 + r;
                    hs[row][col] = f2b(gelu_tanh(hacc[mi][ni][r] + bbv));
                }
            }
        __syncthreads();
        #pragma unroll
        for (int kk = 0; kk < 4; ++kk) {
            s16x8 a[2], bw[4];
            #pragma unroll
            for (int mi = 0; mi < 2; ++mi)
                a[mi] = *(const s16x8*)&hs[wm * 32 + mi * 16 + li][kk * 32 + quad * 8];
            #pragma unroll
            for (int ni = 0; ni < 4; ++ni)
                bw[ni] = *(const s16x8*)&wf2[(long)(wn * 64 + ni * 16 + li) * 512
                                             + hc * 128 + kk * 32 + quad * 8];
            #pragma unroll
            for (int mi = 0; mi < 2; ++mi)
                #pragma unroll
                for (int ni = 0; ni < 4; ++ni)
                    yacc[mi][ni] = MFMA(a[mi], bw[ni], yacc[mi][ni]);
        }
        __syncthreads();
    }
    {
        float f2v[4];
        #pragma unroll
        for (int ni = 0; ni < 4; ++ni) f2v[ni] = fc2_b[cols[ni]];
        #pragma unroll
        for (int mi = 0; mi < 2; ++mi) {
            #pragma unroll
            for (int r = 0; r < 4; ++r) {
                int lrow = wm * 32 + mi * 16 + quad * 4 + r;
                int t = half64 * 64 + lrow;
                int td = t >> 6, th = (t >> 3) & 7, tw = t & 7;
                int d = (wd * 2 + td + 1) & 7, h = (wh * 8 + th + 4) & 63, w = (ww * 8 + tw + 4) & 63;
                long di = (((long)((bb * 8 + d) * 64 + h)) * 64 + w) * 128;
                #pragma unroll
                for (int ni = 0; ni < 4; ++ni) {
                    unsigned int wrd = x1p[mi][ni][r >> 1];
                    float x1v = b2f((ushort)((wrd >> ((r & 1) * 16)) & 0xffffu));
                    out[di + cols[ni]] = x1v + yacc[mi][ni][r] + f2v[ni];
                }
            }
        }
    }
}

// ---------------------------------------------------------------------------
// ws layout (needs ~52.9 MB):
//   [0 .. 50.33MB): qkv window-major [wi][mat][head][tok][16]; K3 overwrites
//                   each window's q-slots in-place per-head with attn-out
//                   (head-major [wi][head][tok][16]).
//   tail: wq 96KB | wp 32KB | wf 256KB | bm 2MB.
// d_out holds ONLY the final f32 output (no scratch -> no races).
// ---------------------------------------------------------------------------
extern "C" void kernel_launch(void* const* d_in, const int* in_sizes, int n_in,
                              void* d_out, int out_size, void* d_ws, size_t ws_size,
                              hipStream_t stream)
{
    (void)in_sizes; (void)n_in; (void)out_size; (void)ws_size;
    const float* x      = (const float*)d_in[0];
    const float* qkv_w  = (const float*)d_in[1];
    const float* qkv_b  = (const float*)d_in[2];
    const float* proj_w = (const float*)d_in[3];
    const float* proj_b = (const float*)d_in[4];
    const float* rpb    = (const float*)d_in[5];
    const float* ln1_g  = (const float*)d_in[6];
    const float* ln1_b  = (const float*)d_in[7];
    const float* ln2_g  = (const float*)d_in[8];
    const float* ln2_b  = (const float*)d_in[9];
    const float* fc1_w  = (const float*)d_in[10];
    const float* fc1_b  = (const float*)d_in[11];
    const float* fc2_w  = (const float*)d_in[12];
    const float* fc2_b  = (const float*)d_in[13];
    float* out = (float*)d_out;

    ushort* qkvb = (ushort*)d_ws;                       // 50.33 MB
    ushort* wq   = (ushort*)((char*)d_ws + 50331648);   // 49152 elems
    ushort* wp   = wq + 49152;                          // 16384
    ushort* wf   = wp + 16384;                          // 131072
    ushort* bm   = wf + 131072;                         // 1048576

    hipLaunchKernelGGL(k0_prep, dim3(832), dim3(256), 0, stream,
                       qkv_w, proj_w, fc1_w, fc2_w, rpb, wq, wp, wf, bm);
    hipLaunchKernelGGL(k2_qkv, dim3(512), dim3(256), 0, stream,
                       x, ln1_g, ln1_b, wq, qkv_b, qkvb);
    hipLaunchKernelGGL(k3_attn, dim3(2048), dim3(64), 0, stream, qkvb, bm);
    hipLaunchKernelGGL(k45, dim3(1024), dim3(256), 0, stream,
                       qkvb, wp, proj_b, x, ln2_g, ln2_b,
                       wf, fc1_b, wf + 65536, fc2_b, out);
}

// Round 4
// 295.330 us; speedup vs baseline: 1.0499x; 1.0499x over previous
//
#include <hip/hip_runtime.h>
#include <math.h>

typedef short s16x8 __attribute__((ext_vector_type(8)));
typedef short s16x4 __attribute__((ext_vector_type(4)));
typedef float f32x4 __attribute__((ext_vector_type(4)));

#define MFMA(a, b, c)    __builtin_amdgcn_mfma_f32_16x16x32_bf16(a, b, c, 0, 0, 0)
#define MFMA16(a, b, c)  __builtin_amdgcn_mfma_f32_16x16x16bf16_1k(a, b, c, 0, 0, 0)

__device__ __forceinline__ float b2f(ushort u) {
    union { unsigned int i; float f; } v; v.i = ((unsigned int)u) << 16; return v.f;
}
__device__ __forceinline__ ushort f2b(float f) {
    union { float f; unsigned int i; } v; v.f = f;
    unsigned int r = v.i + 0x7fffu + ((v.i >> 16) & 1u);
    return (ushort)(r >> 16);
}
__device__ __forceinline__ float gelu_tanh(float v) {
    float u = 0.7978845608f * (v + 0.044715f * v * v * v);
    float e = __expf(-2.f * fabsf(u));
    float t = (1.f - e) / (1.f + e);            // tanh(|u|)
    t = (u < 0.f) ? -t : t;
    return 0.5f * v * (1.f + t);
}

// ---------------------------------------------------------------------------
// K0: all prep. blocks [0,192): qkv_w->wq; [192,256): proj_w->wp;
// [256,768): fc1/fc2->wf; [768,832): bias+mask table bm[cls][head][128][128].
// ---------------------------------------------------------------------------
__global__ __launch_bounds__(256) void k0_prep(
    const float* __restrict__ qkv_w, const float* __restrict__ proj_w,
    const float* __restrict__ fc1_w, const float* __restrict__ fc2_w,
    const float* __restrict__ rpb, ushort* __restrict__ wq,
    ushort* __restrict__ wp, ushort* __restrict__ wf, ushort* __restrict__ bm)
{
    int bid = blockIdx.x, tid = threadIdx.x;
    if (bid < 192) { int idx = bid * 256 + tid; wq[idx] = f2b(qkv_w[idx]); return; }
    if (bid < 256) { int idx = (bid - 192) * 256 + tid; wp[idx] = f2b(proj_w[idx]); return; }
    if (bid < 768) {
        int idx = (bid - 256) * 256 + tid;
        wf[idx] = f2b(idx < 65536 ? fc1_w[idx] : fc2_w[idx - 65536]);
        return;
    }
    int bi = bid - 768;                             // [0,64) = cls*8+head
    int cls = bi >> 3, head = bi & 7;
    int ed = (cls >> 2) & 1, eh = (cls >> 1) & 1, ew = cls & 1;
    int j = tid & 127;
    int tdj = j >> 6, thj = (j >> 3) & 7, twj = j & 7;
    int regj = (ed ? (tdj + 1) : 0) * 9
             + (eh ? ((thj < 4) ? 1 : 2) : 0) * 3
             + (ew ? ((twj < 4) ? 1 : 2) : 0);
    ushort* bmp = bm + (long)bi * 16384;
    for (int ii = 0; ii < 64; ++ii) {
        int i = (tid >> 7) * 64 + ii;
        int tdi = i >> 6, thi = (i >> 3) & 7, twi = i & 7;
        int regi = (ed ? (tdi + 1) : 0) * 9
                 + (eh ? ((thi < 4) ? 1 : 2) : 0) * 3
                 + (ew ? ((twi < 4) ? 1 : 2) : 0);
        int rpi = (tdi - tdj + 1) * 225 + (thi - thj + 7) * 15 + (twi - twj + 7);
        float v = rpb[rpi * 8 + head] + ((regi != regj) ? -100.f : 0.f);
        bmp[i * 128 + j] = f2b(v);
    }
}

// ---------------------------------------------------------------------------
// K2: fused LN1 + cyclic-shift + window gather + QKV GEMM.
// Output WINDOW-major: qkv[wi][mat][head][token][16] (strides 49152/16384/2048/16).
// ---------------------------------------------------------------------------
__global__ __launch_bounds__(256) void k2_qkv(
    const float* __restrict__ x, const float* __restrict__ g,
    const float* __restrict__ be, const ushort* __restrict__ wq,
    const float* __restrict__ qkv_b, ushort* __restrict__ qkv)
{
    __shared__ __align__(16) ushort As[128][136];
    int tid = threadIdx.x;
    int m0 = blockIdx.x * 128;
    {   // LN + shift + gather -> As (2 threads per row)
        int row = tid >> 1, half = tid & 1;
        int tk = m0 + row;
        int wi = tk >> 7, t = tk & 127;
        int b = wi >> 8, wd = (wi >> 6) & 3, wh = (wi >> 3) & 7, ww = wi & 7;
        int td = t >> 6, th = (t >> 3) & 7, tw = t & 7;
        int d = (wd * 2 + td + 1) & 7;
        int h = (wh * 8 + th + 4) & 63;
        int w = (ww * 8 + tw + 4) & 63;
        long src = (((long)((b * 8 + d) * 64 + h)) * 64 + w) * 128 + half * 64;
        float vals[64];
        float s = 0.f, q = 0.f;
        #pragma unroll
        for (int i = 0; i < 16; ++i) {
            float4 u = *(const float4*)&x[src + i * 4];
            vals[i * 4 + 0] = u.x; vals[i * 4 + 1] = u.y;
            vals[i * 4 + 2] = u.z; vals[i * 4 + 3] = u.w;
            s += u.x + u.y + u.z + u.w;
            q += u.x * u.x + u.y * u.y + u.z * u.z + u.w * u.w;
        }
        s += __shfl_xor(s, 1);
        q += __shfl_xor(q, 1);
        float mean = s * (1.f / 128.f);
        float rstd = rsqrtf(q * (1.f / 128.f) - mean * mean + 1e-5f);
        #pragma unroll
        for (int i = 0; i < 8; ++i) {
            ushort pk[8];
            #pragma unroll
            for (int jj = 0; jj < 8; ++jj) {
                int c = half * 64 + i * 8 + jj;
                pk[jj] = f2b((vals[i * 8 + jj] - mean) * rstd * g[c] + be[c]);
            }
            *(uint4*)&As[row][half * 64 + i * 8] = *(uint4*)pk;
        }
    }
    __syncthreads();
    int wv = tid >> 6, lane = tid & 63, li = lane & 15, quad = lane >> 4;
    int wm = wv >> 1, wn = wv & 1;
    long wibase = (long)(m0 >> 7) * 49152;
    for (int nb = 0; nb < 3; ++nb) {
        f32x4 acc[4][4] = {};
        for (int s = 0; s < 4; ++s) {
            s16x8 a[4], bw[4];
            #pragma unroll
            for (int mi = 0; mi < 4; ++mi)
                a[mi] = *(const s16x8*)&As[wm * 64 + mi * 16 + li][s * 32 + quad * 8];
            #pragma unroll
            for (int ni = 0; ni < 4; ++ni)
                bw[ni] = *(const s16x8*)&wq[(long)(nb * 128 + wn * 64 + ni * 16 + li) * 128
                                            + s * 32 + quad * 8];
            #pragma unroll
            for (int mi = 0; mi < 4; ++mi)
                #pragma unroll
                for (int ni = 0; ni < 4; ++ni)
                    acc[mi][ni] = MFMA(a[mi], bw[ni], acc[mi][ni]);
        }
        #pragma unroll
        for (int mi = 0; mi < 4; ++mi)
            #pragma unroll
            for (int ni = 0; ni < 4; ++ni) {
                int gcol = nb * 128 + wn * 64 + ni * 16 + li;
                int mat = gcol >> 7, hd = (gcol >> 4) & 7;
                float bias = qkv_b[gcol];
                float scale = (mat == 0) ? 0.25f : 1.f;   // SCALE = 16^-0.5
                long base2 = wibase + mat * 16384 + hd * 2048 + li;
                #pragma unroll
                for (int r = 0; r < 4; ++r) {
                    int trow = wm * 64 + mi * 16 + quad * 4 + r;
                    qkv[base2 + trow * 16] = f2b((acc[mi][ni][r] + bias) * scale);
                }
            }
    }
}

// ---------------------------------------------------------------------------
// K3 (R4): head-parallel. grid = 512 windows x 4 quarters x 8 heads = 16384
// one-wave blocks; each block = one (window, 32 q-rows, head): stage V once,
// one barrier, one QK^T/softmax/PV pass. 8x less serial work per wave, ~2-4x
// more resident waves/CU -> latency hidden. Same math as R3 (verified):
// swapped QK^T via mfma16 (K=16 exact), P stays in registers, no row-max,
// 1/sum folded into PV output. O written head-major over own q-rows.
// ---------------------------------------------------------------------------
__global__ __launch_bounds__(64) void k3_attn(
    ushort* __restrict__ qkv, const ushort* __restrict__ bm)
{
    __shared__ __align__(16) ushort vt[16][136];
    int b = blockIdx.x;
    int h = b & 7, qq = (b >> 3) & 3, wi = b >> 5;
    int wd = (wi >> 6) & 3, wh = (wi >> 3) & 7, ww = wi & 7;
    int cls = ((wd == 3) << 2) | ((wh == 7) << 1) | (ww == 7);
    int lane = threadIdx.x;
    int li = lane & 15, quad = lane >> 4;
    long hb = (long)wi * 49152 + h * 2048;
    int row0 = qq * 32;
    #pragma unroll
    for (int t2 = 0; t2 < 2; ++t2) {
        int tok = t2 * 64 + lane;
        const ushort* vp = &qkv[hb + 32768 + tok * 16];
        uint4 v0 = *(const uint4*)vp;
        uint4 v1 = *(const uint4*)(vp + 8);
        const ushort* p0 = (const ushort*)&v0;
        const ushort* p1 = (const ushort*)&v1;
        #pragma unroll
        for (int j = 0; j < 8; ++j) { vt[j][tok] = p0[j]; vt[8 + j][tok] = p1[j]; }
    }
    s16x4 qf0 = *(const s16x4*)&qkv[hb + (row0 + li) * 16 + quad * 4];
    s16x4 qf1 = *(const s16x4*)&qkv[hb + (row0 + 16 + li) * 16 + quad * 4];
    __syncthreads();
    long bmb = (long)(cls * 8 + h) * 16384;
    float ps0 = 0.f, ps1 = 0.f;
    uint pa0[8][2], pa1[8][2];
    #pragma unroll
    for (int mi = 0; mi < 8; ++mi) {
        s16x4 kf = *(const s16x4*)&qkv[hb + 16384 + (mi * 16 + li) * 16 + quad * 4];
        f32x4 z = {0.f, 0.f, 0.f, 0.f};
        f32x4 s0 = MFMA16(kf, qf0, z);
        f32x4 s1 = MFMA16(kf, qf1, z);
        s16x4 b0 = *(const s16x4*)&bm[bmb + (row0 + li) * 128 + mi * 16 + quad * 4];
        s16x4 b1 = *(const s16x4*)&bm[bmb + (row0 + 16 + li) * 128 + mi * 16 + quad * 4];
        float e0 = __expf(s0[0] + b2f((ushort)b0[0]));
        float e1 = __expf(s0[1] + b2f((ushort)b0[1]));
        float e2 = __expf(s0[2] + b2f((ushort)b0[2]));
        float e3 = __expf(s0[3] + b2f((ushort)b0[3]));
        ps0 += (e0 + e1) + (e2 + e3);
        pa0[mi][0] = (uint)f2b(e0) | ((uint)f2b(e1) << 16);
        pa0[mi][1] = (uint)f2b(e2) | ((uint)f2b(e3) << 16);
        float f0 = __expf(s1[0] + b2f((ushort)b1[0]));
        float f1 = __expf(s1[1] + b2f((ushort)b1[1]));
        float f2 = __expf(s1[2] + b2f((ushort)b1[2]));
        float f3 = __expf(s1[3] + b2f((ushort)b1[3]));
        ps1 += (f0 + f1) + (f2 + f3);
        pa1[mi][0] = (uint)f2b(f0) | ((uint)f2b(f1) << 16);
        pa1[mi][1] = (uint)f2b(f2) | ((uint)f2b(f3) << 16);
    }
    ps0 += __shfl_xor(ps0, 16); ps0 += __shfl_xor(ps0, 32);
    ps1 += __shfl_xor(ps1, 16); ps1 += __shfl_xor(ps1, 32);
    float inv0 = 1.f / ps0, inv1 = 1.f / ps1;
    f32x4 pc0 = {0.f, 0.f, 0.f, 0.f}, pc1 = {0.f, 0.f, 0.f, 0.f};
    #pragma unroll
    for (int mi = 0; mi < 8; ++mi) {
        s16x4 vf = *(const s16x4*)&vt[li][mi * 16 + quad * 4];
        union { uint2 u; s16x4 v; } a0, a1;
        a0.u.x = pa0[mi][0]; a0.u.y = pa0[mi][1];
        a1.u.x = pa1[mi][0]; a1.u.y = pa1[mi][1];
        pc0 = MFMA16(a0.v, vf, pc0);
        pc1 = MFMA16(a1.v, vf, pc1);
    }
    #pragma unroll
    for (int r = 0; r < 4; ++r) {
        float oi0 = __shfl(inv0, quad * 4 + r);
        float oi1 = __shfl(inv1, quad * 4 + r);
        int i0 = row0 + quad * 4 + r;
        int i1 = row0 + 16 + quad * 4 + r;
        qkv[hb + (long)i0 * 16 + li] = f2b(pc0[r] * oi0);
        qkv[hb + (long)i1 * 16 + li] = f2b(pc1[r] * oi1);
    }
}

// ---------------------------------------------------------------------------
// K45 (R4): full-window tile. 512 blocks x 512 threads (8 waves, wm 0..3).
// B-operand (wp/wf1/wf2) L2 traffic halves vs 64-token tile; barriers per
// token halve; LDS 69.6KB -> 2 blocks/CU = 16 waves/CU. Inner MFMA structure
// identical to R2 (112 VGPR, no spill).
// ---------------------------------------------------------------------------
__global__ __launch_bounds__(512) void k45(
    const ushort* __restrict__ ao, const ushort* __restrict__ wp,
    const float* __restrict__ proj_b, const float* __restrict__ x,
    const float* __restrict__ g2, const float* __restrict__ be2,
    const ushort* __restrict__ wf1, const float* __restrict__ fc1_b,
    const ushort* __restrict__ wf2, const float* __restrict__ fc2_b,
    float* __restrict__ out)
{
    __shared__ __align__(16) ushort As[128][132];   // ao tile, later xs (LN2 out)
    __shared__ __align__(16) ushort hs[128][132];   // gelu(h) chunk
    __shared__ float redS[2][128];
    __shared__ float redQ[2][128];
    int tid = threadIdx.x;
    int wi = blockIdx.x;
    int wd = (wi >> 6) & 3, wh = (wi >> 3) & 7, ww = wi & 7;
    int bb = wi >> 8;
    long aob = (long)wi * 49152;
    #pragma unroll
    for (int i = 0; i < 4; ++i) {
        int slot = tid + i * 512;               // 0..2047
        int row = slot & 127, hsl = slot >> 7;  // hsl = head*2 + (d-half)
        *(uint4*)&As[row][hsl * 8] =
            *(const uint4*)&ao[aob + (hsl >> 1) * 2048 + (long)row * 16 + (hsl & 1) * 8];
    }
    __syncthreads();
    int wv = tid >> 6, lane = tid & 63, li = lane & 15, quad = lane >> 4;
    int wm = wv >> 1, wn = wv & 1;              // wm 0..3, wn 0..1
    f32x4 acc[2][4] = {};
    for (int s = 0; s < 4; ++s) {
        s16x8 a[2], bw[4];
        #pragma unroll
        for (int mi = 0; mi < 2; ++mi)
            a[mi] = *(const s16x8*)&As[wm * 32 + mi * 16 + li][s * 32 + quad * 8];
        #pragma unroll
        for (int ni = 0; ni < 4; ++ni)
            bw[ni] = *(const s16x8*)&wp[(long)(wn * 64 + ni * 16 + li) * 128 + s * 32 + quad * 8];
        #pragma unroll
        for (int mi = 0; mi < 2; ++mi)
            #pragma unroll
            for (int ni = 0; ni < 4; ++ni)
                acc[mi][ni] = MFMA(a[mi], bw[ni], acc[mi][ni]);
    }
    // epilogue: x1 = acc + proj_b + x (f32, in-place in acc); LN2 row partials
    int cols[4];
    #pragma unroll
    for (int ni = 0; ni < 4; ++ni) cols[ni] = wn * 64 + ni * 16 + li;
    {
        float pbv[4];
        #pragma unroll
        for (int ni = 0; ni < 4; ++ni) pbv[ni] = proj_b[cols[ni]];
        #pragma unroll
        for (int mi = 0; mi < 2; ++mi) {
            #pragma unroll
            for (int r = 0; r < 4; ++r) {
                int t = wm * 32 + mi * 16 + quad * 4 + r;     // 0..127
                int td = t >> 6, th = (t >> 3) & 7, tw = t & 7;
                int d = (wd * 2 + td + 1) & 7, h = (wh * 8 + th + 4) & 63, w = (ww * 8 + tw + 4) & 63;
                long di = (((long)((bb * 8 + d) * 64 + h)) * 64 + w) * 128;
                float s_ = 0.f, q_ = 0.f;
                #pragma unroll
                for (int ni = 0; ni < 4; ++ni) {
                    float v = acc[mi][ni][r] + pbv[ni] + x[di + cols[ni]];
                    acc[mi][ni][r] = v;
                    s_ += v; q_ += v * v;
                }
                #pragma unroll
                for (int m = 1; m < 16; m <<= 1) {
                    s_ += __shfl_xor(s_, m);
                    q_ += __shfl_xor(q_, m);
                }
                if (li == 0) { redS[wn][t] = s_; redQ[wn][t] = q_; }
            }
        }
    }
    __syncthreads();
    // LN2 normalize -> As (xs); pack x1 -> bf16x2 regs
    {
        float g2v[4], be2v[4];
        #pragma unroll
        for (int ni = 0; ni < 4; ++ni) { g2v[ni] = g2[cols[ni]]; be2v[ni] = be2[cols[ni]]; }
        #pragma unroll
        for (int mi = 0; mi < 2; ++mi) {
            #pragma unroll
            for (int r = 0; r < 4; ++r) {
                int t = wm * 32 + mi * 16 + quad * 4 + r;
                float tS = redS[0][t] + redS[1][t];
                float tQ = redQ[0][t] + redQ[1][t];
                float mean = tS * (1.f / 128.f);
                float rstd = rsqrtf(tQ * (1.f / 128.f) - mean * mean + 1e-5f);
                #pragma unroll
                for (int ni = 0; ni < 4; ++ni)
                    As[t][cols[ni]] = f2b((acc[mi][ni][r] - mean) * rstd * g2v[ni] + be2v[ni]);
            }
        }
    }
    uint x1p[2][4][2];
    #pragma unroll
    for (int mi = 0; mi < 2; ++mi)
        #pragma unroll
        for (int ni = 0; ni < 4; ++ni)
            #pragma unroll
            for (int rr = 0; rr < 2; ++rr)
                x1p[mi][ni][rr] = (unsigned int)f2b(acc[mi][ni][2 * rr])
                                | ((unsigned int)f2b(acc[mi][ni][2 * rr + 1]) << 16);
    __syncthreads();
    f32x4 yacc[2][4] = {};
    for (int hc = 0; hc < 4; ++hc) {
        f32x4 hacc[2][4] = {};
        #pragma unroll
        for (int kk = 0; kk < 4; ++kk) {
            s16x8 a[2], bw[4];
            #pragma unroll
            for (int mi = 0; mi < 2; ++mi)
                a[mi] = *(const s16x8*)&As[wm * 32 + mi * 16 + li][kk * 32 + quad * 8];
            #pragma unroll
            for (int ni = 0; ni < 4; ++ni)
                bw[ni] = *(const s16x8*)&wf1[(long)(hc * 128 + wn * 64 + ni * 16 + li) * 128
                                             + kk * 32 + quad * 8];
            #pragma unroll
            for (int mi = 0; mi < 2; ++mi)
                #pragma unroll
                for (int ni = 0; ni < 4; ++ni)
                    hacc[mi][ni] = MFMA(a[mi], bw[ni], hacc[mi][ni]);
        }
        #pragma unroll
        for (int mi = 0; mi < 2; ++mi)
            #pragma unroll
            for (int ni = 0; ni < 4; ++ni) {
                int col = wn * 64 + ni * 16 + li;
                float bbv = fc1_b[hc * 128 + col];
                #pragma unroll
                for (int r = 0; r < 4; ++r) {
                    int row = wm * 32 + mi * 16 + quad * 4 + r;
                    hs[row][col] = f2b(gelu_tanh(hacc[mi][ni][r] + bbv));
                }
            }
        __syncthreads();
        #pragma unroll
        for (int kk = 0; kk < 4; ++kk) {
            s16x8 a[2], bw[4];
            #pragma unroll
            for (int mi = 0; mi < 2; ++mi)
                a[mi] = *(const s16x8*)&hs[wm * 32 + mi * 16 + li][kk * 32 + quad * 8];
            #pragma unroll
            for (int ni = 0; ni < 4; ++ni)
                bw[ni] = *(const s16x8*)&wf2[(long)(wn * 64 + ni * 16 + li) * 512
                                             + hc * 128 + kk * 32 + quad * 8];
            #pragma unroll
            for (int mi = 0; mi < 2; ++mi)
                #pragma unroll
                for (int ni = 0; ni < 4; ++ni)
                    yacc[mi][ni] = MFMA(a[mi], bw[ni], yacc[mi][ni]);
        }
        __syncthreads();
    }
    {
        float f2v[4];
        #pragma unroll
        for (int ni = 0; ni < 4; ++ni) f2v[ni] = fc2_b[cols[ni]];
        #pragma unroll
        for (int mi = 0; mi < 2; ++mi) {
            #pragma unroll
            for (int r = 0; r < 4; ++r) {
                int t = wm * 32 + mi * 16 + quad * 4 + r;
                int td = t >> 6, th = (t >> 3) & 7, tw = t & 7;
                int d = (wd * 2 + td + 1) & 7, h = (wh * 8 + th + 4) & 63, w = (ww * 8 + tw + 4) & 63;
                long di = (((long)((bb * 8 + d) * 64 + h)) * 64 + w) * 128;
                #pragma unroll
                for (int ni = 0; ni < 4; ++ni) {
                    unsigned int wrd = x1p[mi][ni][r >> 1];
                    float x1v = b2f((ushort)((wrd >> ((r & 1) * 16)) & 0xffffu));
                    out[di + cols[ni]] = x1v + yacc[mi][ni][r] + f2v[ni];
                }
            }
        }
    }
}

// ---------------------------------------------------------------------------
// ws layout (needs ~52.9 MB):
//   [0 .. 50.33MB): qkv window-major [wi][mat][head][tok][16]; K3 overwrites
//                   each window's q-slots in-place per-head with attn-out
//                   (head-major [wi][head][tok][16]).
//   tail: wq 96KB | wp 32KB | wf 256KB | bm 2MB.
// d_out holds ONLY the final f32 output (no scratch -> no races).
// ---------------------------------------------------------------------------
extern "C" void kernel_launch(void* const* d_in, const int* in_sizes, int n_in,
                              void* d_out, int out_size, void* d_ws, size_t ws_size,
                              hipStream_t stream)
{
    (void)in_sizes; (void)n_in; (void)out_size; (void)ws_size;
    const float* x      = (const float*)d_in[0];
    const float* qkv_w  = (const float*)d_in[1];
    const float* qkv_b  = (const float*)d_in[2];
    const float* proj_w = (const float*)d_in[3];
    const float* proj_b = (const float*)d_in[4];
    const float* rpb    = (const float*)d_in[5];
    const float* ln1_g  = (const float*)d_in[6];
    const float* ln1_b  = (const float*)d_in[7];
    const float* ln2_g  = (const float*)d_in[8];
    const float* ln2_b  = (const float*)d_in[9];
    const float* fc1_w  = (const float*)d_in[10];
    const float* fc1_b  = (const float*)d_in[11];
    const float* fc2_w  = (const float*)d_in[12];
    const float* fc2_b  = (const float*)d_in[13];
    float* out = (float*)d_out;

    ushort* qkvb = (ushort*)d_ws;                       // 50.33 MB
    ushort* wq   = (ushort*)((char*)d_ws + 50331648);   // 49152 elems
    ushort* wp   = wq + 49152;                          // 16384
    ushort* wf   = wp + 16384;                          // 131072
    ushort* bm   = wf + 131072;                         // 1048576

    hipLaunchKernelGGL(k0_prep, dim3(832), dim3(256), 0, stream,
                       qkv_w, proj_w, fc1_w, fc2_w, rpb, wq, wp, wf, bm);
    hipLaunchKernelGGL(k2_qkv, dim3(512), dim3(256), 0, stream,
                       x, ln1_g, ln1_b, wq, qkv_b, qkvb);
    hipLaunchKernelGGL(k3_attn, dim3(16384), dim3(64), 0, stream, qkvb, bm);
    hipLaunchKernelGGL(k45, dim3(512), dim3(512), 0, stream,
                       qkvb, wp, proj_b, x, ln2_g, ln2_b,
                       wf, fc1_b, wf + 65536, fc2_b, out);
}

// Round 5
// 282.958 us; speedup vs baseline: 1.0958x; 1.0437x over previous
//
#include <hip/hip_runtime.h>
#include <math.h>

typedef short s16x8 __attribute__((ext_vector_type(8)));
typedef short s16x4 __attribute__((ext_vector_type(4)));
typedef float f32x4 __attribute__((ext_vector_type(4)));

#define MFMA(a, b, c)    __builtin_amdgcn_mfma_f32_16x16x32_bf16(a, b, c, 0, 0, 0)
#define MFMA16(a, b, c)  __builtin_amdgcn_mfma_f32_16x16x16bf16_1k(a, b, c, 0, 0, 0)

__device__ __forceinline__ float b2f(ushort u) {
    union { unsigned int i; float f; } v; v.i = ((unsigned int)u) << 16; return v.f;
}
__device__ __forceinline__ ushort f2b(float f) {
    union { float f; unsigned int i; } v; v.f = f;
    unsigned int r = v.i + 0x7fffu + ((v.i >> 16) & 1u);
    return (ushort)(r >> 16);
}
__device__ __forceinline__ float gelu_tanh(float v) {
    float u = 0.7978845608f * (v + 0.044715f * v * v * v);
    float e = __expf(-2.f * fabsf(u));
    float t = (1.f - e) / (1.f + e);            // tanh(|u|)
    t = (u < 0.f) ? -t : t;
    return 0.5f * v * (1.f + t);
}

// ---------------------------------------------------------------------------
// K0: all prep. blocks [0,192): qkv_w->wq; [192,256): proj_w->wp;
// [256,768): fc1/fc2->wf; [768,832): bias+mask table bm[cls][head][128][128].
// ---------------------------------------------------------------------------
__global__ __launch_bounds__(256) void k0_prep(
    const float* __restrict__ qkv_w, const float* __restrict__ proj_w,
    const float* __restrict__ fc1_w, const float* __restrict__ fc2_w,
    const float* __restrict__ rpb, ushort* __restrict__ wq,
    ushort* __restrict__ wp, ushort* __restrict__ wf, ushort* __restrict__ bm)
{
    int bid = blockIdx.x, tid = threadIdx.x;
    if (bid < 192) { int idx = bid * 256 + tid; wq[idx] = f2b(qkv_w[idx]); return; }
    if (bid < 256) { int idx = (bid - 192) * 256 + tid; wp[idx] = f2b(proj_w[idx]); return; }
    if (bid < 768) {
        int idx = (bid - 256) * 256 + tid;
        wf[idx] = f2b(idx < 65536 ? fc1_w[idx] : fc2_w[idx - 65536]);
        return;
    }
    int bi = bid - 768;                             // [0,64) = cls*8+head
    int cls = bi >> 3, head = bi & 7;
    int ed = (cls >> 2) & 1, eh = (cls >> 1) & 1, ew = cls & 1;
    int j = tid & 127;
    int tdj = j >> 6, thj = (j >> 3) & 7, twj = j & 7;
    int regj = (ed ? (tdj + 1) : 0) * 9
             + (eh ? ((thj < 4) ? 1 : 2) : 0) * 3
             + (ew ? ((twj < 4) ? 1 : 2) : 0);
    ushort* bmp = bm + (long)bi * 16384;
    for (int ii = 0; ii < 64; ++ii) {
        int i = (tid >> 7) * 64 + ii;
        int tdi = i >> 6, thi = (i >> 3) & 7, twi = i & 7;
        int regi = (ed ? (tdi + 1) : 0) * 9
                 + (eh ? ((thi < 4) ? 1 : 2) : 0) * 3
                 + (ew ? ((twi < 4) ? 1 : 2) : 0);
        int rpi = (tdi - tdj + 1) * 225 + (thi - thj + 7) * 15 + (twi - twj + 7);
        float v = rpb[rpi * 8 + head] + ((regi != regj) ? -100.f : 0.f);
        bmp[i * 128 + j] = f2b(v);
    }
}

// ---------------------------------------------------------------------------
// K2: fused LN1 + cyclic-shift + window gather + QKV GEMM.
// Output WINDOW-major: qkv[wi][mat][head][token][16] (strides 49152/16384/2048/16).
// ---------------------------------------------------------------------------
__global__ __launch_bounds__(256) void k2_qkv(
    const float* __restrict__ x, const float* __restrict__ g,
    const float* __restrict__ be, const ushort* __restrict__ wq,
    const float* __restrict__ qkv_b, ushort* __restrict__ qkv)
{
    __shared__ __align__(16) ushort As[128][136];
    int tid = threadIdx.x;
    int m0 = blockIdx.x * 128;
    {   // LN + shift + gather -> As (2 threads per row)
        int row = tid >> 1, half = tid & 1;
        int tk = m0 + row;
        int wi = tk >> 7, t = tk & 127;
        int b = wi >> 8, wd = (wi >> 6) & 3, wh = (wi >> 3) & 7, ww = wi & 7;
        int td = t >> 6, th = (t >> 3) & 7, tw = t & 7;
        int d = (wd * 2 + td + 1) & 7;
        int h = (wh * 8 + th + 4) & 63;
        int w = (ww * 8 + tw + 4) & 63;
        long src = (((long)((b * 8 + d) * 64 + h)) * 64 + w) * 128 + half * 64;
        float vals[64];
        float s = 0.f, q = 0.f;
        #pragma unroll
        for (int i = 0; i < 16; ++i) {
            float4 u = *(const float4*)&x[src + i * 4];
            vals[i * 4 + 0] = u.x; vals[i * 4 + 1] = u.y;
            vals[i * 4 + 2] = u.z; vals[i * 4 + 3] = u.w;
            s += u.x + u.y + u.z + u.w;
            q += u.x * u.x + u.y * u.y + u.z * u.z + u.w * u.w;
        }
        s += __shfl_xor(s, 1);
        q += __shfl_xor(q, 1);
        float mean = s * (1.f / 128.f);
        float rstd = rsqrtf(q * (1.f / 128.f) - mean * mean + 1e-5f);
        #pragma unroll
        for (int i = 0; i < 8; ++i) {
            ushort pk[8];
            #pragma unroll
            for (int jj = 0; jj < 8; ++jj) {
                int c = half * 64 + i * 8 + jj;
                pk[jj] = f2b((vals[i * 8 + jj] - mean) * rstd * g[c] + be[c]);
            }
            *(uint4*)&As[row][half * 64 + i * 8] = *(uint4*)pk;
        }
    }
    __syncthreads();
    int wv = tid >> 6, lane = tid & 63, li = lane & 15, quad = lane >> 4;
    int wm = wv >> 1, wn = wv & 1;
    long wibase = (long)(m0 >> 7) * 49152;
    for (int nb = 0; nb < 3; ++nb) {
        f32x4 acc[4][4] = {};
        for (int s = 0; s < 4; ++s) {
            s16x8 a[4], bw[4];
            #pragma unroll
            for (int mi = 0; mi < 4; ++mi)
                a[mi] = *(const s16x8*)&As[wm * 64 + mi * 16 + li][s * 32 + quad * 8];
            #pragma unroll
            for (int ni = 0; ni < 4; ++ni)
                bw[ni] = *(const s16x8*)&wq[(long)(nb * 128 + wn * 64 + ni * 16 + li) * 128
                                            + s * 32 + quad * 8];
            #pragma unroll
            for (int mi = 0; mi < 4; ++mi)
                #pragma unroll
                for (int ni = 0; ni < 4; ++ni)
                    acc[mi][ni] = MFMA(a[mi], bw[ni], acc[mi][ni]);
        }
        #pragma unroll
        for (int mi = 0; mi < 4; ++mi)
            #pragma unroll
            for (int ni = 0; ni < 4; ++ni) {
                int gcol = nb * 128 + wn * 64 + ni * 16 + li;
                int mat = gcol >> 7, hd = (gcol >> 4) & 7;
                float bias = qkv_b[gcol];
                float scale = (mat == 0) ? 0.25f : 1.f;   // SCALE = 16^-0.5
                long base2 = wibase + mat * 16384 + hd * 2048 + li;
                #pragma unroll
                for (int r = 0; r < 4; ++r) {
                    int trow = wm * 64 + mi * 16 + quad * 4 + r;
                    qkv[base2 + trow * 16] = f2b((acc[mi][ni][r] + bias) * scale);
                }
            }
    }
}

// ---------------------------------------------------------------------------
// K3 (R5): one block per (window, head), grid 4096 x 64 threads. K and V^T
// staged in LDS ONCE (K/V read 1x instead of 4x: qkvb traffic ~164->~70MB),
// then 4 quarter-passes (32 q-rows each) run back-to-back with NO barriers
// (passes independent; O-writes of pass q touch rows later passes never
// read). Same verified math as R4: swapped QK^T via mfma16 (K=16 exact),
// P in registers, no row-max, 1/sum folded into PV output.
// ---------------------------------------------------------------------------
__global__ __launch_bounds__(64) void k3_attn(
    ushort* __restrict__ qkv, const ushort* __restrict__ bm)
{
    __shared__ __align__(16) ushort vt[16][136];   // V^T [d][tok]
    __shared__ __align__(16) ushort ks[128][24];   // K [tok][d], padded rows (48B)
    int b = blockIdx.x;
    int h = b & 7, wi = b >> 3;
    int wd = (wi >> 6) & 3, wh = (wi >> 3) & 7, ww = wi & 7;
    int cls = ((wd == 3) << 2) | ((wh == 7) << 1) | (ww == 7);
    int lane = threadIdx.x;
    int li = lane & 15, quad = lane >> 4;
    long hb = (long)wi * 49152 + h * 2048;
    #pragma unroll
    for (int t2 = 0; t2 < 2; ++t2) {
        int tok = t2 * 64 + lane;
        const ushort* vp = &qkv[hb + 32768 + tok * 16];
        uint4 v0 = *(const uint4*)vp;
        uint4 v1 = *(const uint4*)(vp + 8);
        const ushort* p0 = (const ushort*)&v0;
        const ushort* p1 = (const ushort*)&v1;
        #pragma unroll
        for (int j = 0; j < 8; ++j) { vt[j][tok] = p0[j]; vt[8 + j][tok] = p1[j]; }
        const ushort* kp = &qkv[hb + 16384 + tok * 16];
        *(uint4*)&ks[tok][0] = *(const uint4*)kp;
        *(uint4*)&ks[tok][8] = *(const uint4*)(kp + 8);
    }
    __syncthreads();
    long bmb = (long)(cls * 8 + h) * 16384;
    for (int qq = 0; qq < 4; ++qq) {
        int row0 = qq * 32;
        s16x4 qf0 = *(const s16x4*)&qkv[hb + (row0 + li) * 16 + quad * 4];
        s16x4 qf1 = *(const s16x4*)&qkv[hb + (row0 + 16 + li) * 16 + quad * 4];
        float ps0 = 0.f, ps1 = 0.f;
        uint pa0[8][2], pa1[8][2];
        #pragma unroll
        for (int mi = 0; mi < 8; ++mi) {
            s16x4 kf = *(const s16x4*)&ks[mi * 16 + li][quad * 4];
            f32x4 z = {0.f, 0.f, 0.f, 0.f};
            f32x4 s0 = MFMA16(kf, qf0, z);
            f32x4 s1 = MFMA16(kf, qf1, z);
            s16x4 b0 = *(const s16x4*)&bm[bmb + (row0 + li) * 128 + mi * 16 + quad * 4];
            s16x4 b1 = *(const s16x4*)&bm[bmb + (row0 + 16 + li) * 128 + mi * 16 + quad * 4];
            float e0 = __expf(s0[0] + b2f((ushort)b0[0]));
            float e1 = __expf(s0[1] + b2f((ushort)b0[1]));
            float e2 = __expf(s0[2] + b2f((ushort)b0[2]));
            float e3 = __expf(s0[3] + b2f((ushort)b0[3]));
            ps0 += (e0 + e1) + (e2 + e3);
            pa0[mi][0] = (uint)f2b(e0) | ((uint)f2b(e1) << 16);
            pa0[mi][1] = (uint)f2b(e2) | ((uint)f2b(e3) << 16);
            float f0 = __expf(s1[0] + b2f((ushort)b1[0]));
            float f1 = __expf(s1[1] + b2f((ushort)b1[1]));
            float f2 = __expf(s1[2] + b2f((ushort)b1[2]));
            float f3 = __expf(s1[3] + b2f((ushort)b1[3]));
            ps1 += (f0 + f1) + (f2 + f3);
            pa1[mi][0] = (uint)f2b(f0) | ((uint)f2b(f1) << 16);
            pa1[mi][1] = (uint)f2b(f2) | ((uint)f2b(f3) << 16);
        }
        ps0 += __shfl_xor(ps0, 16); ps0 += __shfl_xor(ps0, 32);
        ps1 += __shfl_xor(ps1, 16); ps1 += __shfl_xor(ps1, 32);
        float inv0 = 1.f / ps0, inv1 = 1.f / ps1;
        f32x4 pc0 = {0.f, 0.f, 0.f, 0.f}, pc1 = {0.f, 0.f, 0.f, 0.f};
        #pragma unroll
        for (int mi = 0; mi < 8; ++mi) {
            s16x4 vf = *(const s16x4*)&vt[li][mi * 16 + quad * 4];
            union { uint2 u; s16x4 v; } a0, a1;
            a0.u.x = pa0[mi][0]; a0.u.y = pa0[mi][1];
            a1.u.x = pa1[mi][0]; a1.u.y = pa1[mi][1];
            pc0 = MFMA16(a0.v, vf, pc0);
            pc1 = MFMA16(a1.v, vf, pc1);
        }
        #pragma unroll
        for (int r = 0; r < 4; ++r) {
            float oi0 = __shfl(inv0, quad * 4 + r);
            float oi1 = __shfl(inv1, quad * 4 + r);
            int i0 = row0 + quad * 4 + r;
            int i1 = row0 + 16 + quad * 4 + r;
            qkv[hb + (long)i0 * 16 + li] = f2b(pc0[r] * oi0);
            qkv[hb + (long)i1 * 16 + li] = f2b(pc1[r] * oi1);
        }
    }
}

// ---------------------------------------------------------------------------
// K45 (R5): revert to the R0-proven shape (103.4us measured): 64-token tile,
// 1024 blocks x 256 threads, x1 kept in x1t LDS (VGPR 96, no spill), LDS
// 52.7KB. Only the staging loop differs from R0: ao is head-major
// [wi][head][tok][16] now, regathered into As[tok][128ch] (R3-proven).
// ---------------------------------------------------------------------------
__global__ __launch_bounds__(256) void k45(
    const ushort* __restrict__ ao, const ushort* __restrict__ wp,
    const float* __restrict__ proj_b, const float* __restrict__ x,
    const float* __restrict__ g2, const float* __restrict__ be2,
    const ushort* __restrict__ wf1, const float* __restrict__ fc1_b,
    const ushort* __restrict__ wf2, const float* __restrict__ fc2_b,
    float* __restrict__ out)
{
    __shared__ __align__(16) ushort As[64][132];    // ao tile, later xs (LN2 out)
    __shared__ __align__(16) ushort x1t[64][132];   // x1 (bf16)
    __shared__ __align__(16) ushort hs[64][132];    // gelu(h) chunk
    __shared__ float redS[4][64];
    __shared__ float redQ[4][64];
    int tid = threadIdx.x;
    int b = blockIdx.x;
    int wi = b >> 1, half64 = b & 1;
    int wd = (wi >> 6) & 3, wh = (wi >> 3) & 7, ww = wi & 7;
    int bb = wi >> 8;
    long aob = (long)wi * 49152;
    int tok0 = half64 * 64;
    #pragma unroll
    for (int i = 0; i < 4; ++i) {
        int slot = tid + i * 256;               // 0..1023
        int row = slot & 63, hsl = slot >> 6;   // hsl = head*2 + (d-half)
        *(uint4*)&As[row][hsl * 8] =
            *(const uint4*)&ao[aob + (hsl >> 1) * 2048 + (long)(tok0 + row) * 16 + (hsl & 1) * 8];
    }
    __syncthreads();
    int wv = tid >> 6, lane = tid & 63, li = lane & 15, quad = lane >> 4;
    int wm = wv >> 1, wn = wv & 1;
    f32x4 acc[2][4] = {};
    for (int s = 0; s < 4; ++s) {
        s16x8 a[2], bw[4];
        #pragma unroll
        for (int mi = 0; mi < 2; ++mi)
            a[mi] = *(const s16x8*)&As[wm * 32 + mi * 16 + li][s * 32 + quad * 8];
        #pragma unroll
        for (int ni = 0; ni < 4; ++ni)
            bw[ni] = *(const s16x8*)&wp[(long)(wn * 64 + ni * 16 + li) * 128 + s * 32 + quad * 8];
        #pragma unroll
        for (int mi = 0; mi < 2; ++mi)
            #pragma unroll
            for (int ni = 0; ni < 4; ++ni)
                acc[mi][ni] = MFMA(a[mi], bw[ni], acc[mi][ni]);
    }
    // epilogue: residual add (f32 x) -> x1t (bf16)
    #pragma unroll
    for (int mi = 0; mi < 2; ++mi) {
        #pragma unroll
        for (int r = 0; r < 4; ++r) {
            int lrow = wm * 32 + mi * 16 + quad * 4 + r;
            int t = half64 * 64 + lrow;
            int td = t >> 6, th = (t >> 3) & 7, tw = t & 7;
            int d = (wd * 2 + td + 1) & 7, h = (wh * 8 + th + 4) & 63, w = (ww * 8 + tw + 4) & 63;
            long di = (((long)((bb * 8 + d) * 64 + h)) * 64 + w) * 128;
            #pragma unroll
            for (int ni = 0; ni < 4; ++ni) {
                int col = wn * 64 + ni * 16 + li;
                x1t[lrow][col] = f2b(acc[mi][ni][r] + proj_b[col] + x[di + col]);
            }
        }
    }
    __syncthreads();
    {   // LN2 from x1t -> xs (reuse As)
        int token = tid & 63, part = tid >> 6;
        float vals[32];
        float s = 0.f, q = 0.f;
        #pragma unroll
        for (int i = 0; i < 4; ++i) {
            uint4 u = *(const uint4*)&x1t[token][part * 32 + i * 8];
            const ushort* p = (const ushort*)&u;
            #pragma unroll
            for (int j = 0; j < 8; ++j) { float f = b2f(p[j]); vals[i * 8 + j] = f; s += f; q += f * f; }
        }
        redS[part][token] = s; redQ[part][token] = q;
        __syncthreads();
        float st = 0.f, qt = 0.f;
        #pragma unroll
        for (int p2 = 0; p2 < 4; ++p2) { st += redS[p2][token]; qt += redQ[p2][token]; }
        float mean = st * (1.f / 128.f);
        float rstd = rsqrtf(qt * (1.f / 128.f) - mean * mean + 1e-5f);
        #pragma unroll
        for (int i = 0; i < 4; ++i) {
            ushort packed[8];
            #pragma unroll
            for (int j = 0; j < 8; ++j) {
                int c = part * 32 + i * 8 + j;
                packed[j] = f2b((vals[i * 8 + j] - mean) * rstd * g2[c] + be2[c]);
            }
            *(uint4*)&As[token][part * 32 + i * 8] = *(uint4*)packed;
        }
    }
    __syncthreads();
    f32x4 yacc[2][4] = {};
    for (int hc = 0; hc < 4; ++hc) {
        f32x4 hacc[2][4] = {};
        #pragma unroll
        for (int kk = 0; kk < 4; ++kk) {
            s16x8 a[2], bw[4];
            #pragma unroll
            for (int mi = 0; mi < 2; ++mi)
                a[mi] = *(const s16x8*)&As[wm * 32 + mi * 16 + li][kk * 32 + quad * 8];
            #pragma unroll
            for (int ni = 0; ni < 4; ++ni)
                bw[ni] = *(const s16x8*)&wf1[(long)(hc * 128 + wn * 64 + ni * 16 + li) * 128
                                             + kk * 32 + quad * 8];
            #pragma unroll
            for (int mi = 0; mi < 2; ++mi)
                #pragma unroll
                for (int ni = 0; ni < 4; ++ni)
                    hacc[mi][ni] = MFMA(a[mi], bw[ni], hacc[mi][ni]);
        }
        #pragma unroll
        for (int mi = 0; mi < 2; ++mi)
            #pragma unroll
            for (int ni = 0; ni < 4; ++ni) {
                int col = wn * 64 + ni * 16 + li;
                float bbv = fc1_b[hc * 128 + col];
                #pragma unroll
                for (int r = 0; r < 4; ++r) {
                    int row = wm * 32 + mi * 16 + quad * 4 + r;
                    hs[row][col] = f2b(gelu_tanh(hacc[mi][ni][r] + bbv));
                }
            }
        __syncthreads();
        #pragma unroll
        for (int kk = 0; kk < 4; ++kk) {
            s16x8 a[2], bw[4];
            #pragma unroll
            for (int mi = 0; mi < 2; ++mi)
                a[mi] = *(const s16x8*)&hs[wm * 32 + mi * 16 + li][kk * 32 + quad * 8];
            #pragma unroll
            for (int ni = 0; ni < 4; ++ni)
                bw[ni] = *(const s16x8*)&wf2[(long)(wn * 64 + ni * 16 + li) * 512
                                             + hc * 128 + kk * 32 + quad * 8];
            #pragma unroll
            for (int mi = 0; mi < 2; ++mi)
                #pragma unroll
                for (int ni = 0; ni < 4; ++ni)
                    yacc[mi][ni] = MFMA(a[mi], bw[ni], yacc[mi][ni]);
        }
        __syncthreads();
    }
    #pragma unroll
    for (int mi = 0; mi < 2; ++mi) {
        #pragma unroll
        for (int r = 0; r < 4; ++r) {
            int lrow = wm * 32 + mi * 16 + quad * 4 + r;
            int t = half64 * 64 + lrow;
            int td = t >> 6, th = (t >> 3) & 7, tw = t & 7;
            int d = (wd * 2 + td + 1) & 7, h = (wh * 8 + th + 4) & 63, w = (ww * 8 + tw + 4) & 63;
            long di = (((long)((bb * 8 + d) * 64 + h)) * 64 + w) * 128;
            #pragma unroll
            for (int ni = 0; ni < 4; ++ni) {
                int col = wn * 64 + ni * 16 + li;
                out[di + col] = b2f(x1t[lrow][col]) + yacc[mi][ni][r] + fc2_b[col];
            }
        }
    }
}

// ---------------------------------------------------------------------------
// ws layout (needs ~52.9 MB):
//   [0 .. 50.33MB): qkv window-major [wi][mat][head][tok][16]; K3 overwrites
//                   each window's q-slots in-place per-head with attn-out
//                   (head-major [wi][head][tok][16]).
//   tail: wq 96KB | wp 32KB | wf 256KB | bm 2MB.
// d_out holds ONLY the final f32 output (no scratch -> no races).
// ---------------------------------------------------------------------------
extern "C" void kernel_launch(void* const* d_in, const int* in_sizes, int n_in,
                              void* d_out, int out_size, void* d_ws, size_t ws_size,
                              hipStream_t stream)
{
    (void)in_sizes; (void)n_in; (void)out_size; (void)ws_size;
    const float* x      = (const float*)d_in[0];
    const float* qkv_w  = (const float*)d_in[1];
    const float* qkv_b  = (const float*)d_in[2];
    const float* proj_w = (const float*)d_in[3];
    const float* proj_b = (const float*)d_in[4];
    const float* rpb    = (const float*)d_in[5];
    const float* ln1_g  = (const float*)d_in[6];
    const float* ln1_b  = (const float*)d_in[7];
    const float* ln2_g  = (const float*)d_in[8];
    const float* ln2_b  = (const float*)d_in[9];
    const float* fc1_w  = (const float*)d_in[10];
    const float* fc1_b  = (const float*)d_in[11];
    const float* fc2_w  = (const float*)d_in[12];
    const float* fc2_b  = (const float*)d_in[13];
    float* out = (float*)d_out;

    ushort* qkvb = (ushort*)d_ws;                       // 50.33 MB
    ushort* wq   = (ushort*)((char*)d_ws + 50331648);   // 49152 elems
    ushort* wp   = wq + 49152;                          // 16384
    ushort* wf   = wp + 16384;                          // 131072
    ushort* bm   = wf + 131072;                         // 1048576

    hipLaunchKernelGGL(k0_prep, dim3(832), dim3(256), 0, stream,
                       qkv_w, proj_w, fc1_w, fc2_w, rpb, wq, wp, wf, bm);
    hipLaunchKernelGGL(k2_qkv, dim3(512), dim3(256), 0, stream,
                       x, ln1_g, ln1_b, wq, qkv_b, qkvb);
    hipLaunchKernelGGL(k3_attn, dim3(4096), dim3(64), 0, stream, qkvb, bm);
    hipLaunchKernelGGL(k45, dim3(1024), dim3(256), 0, stream,
                       qkvb, wp, proj_b, x, ln2_g, ln2_b,
                       wf, fc1_b, wf + 65536, fc2_b, out);
}

// Round 6
// 269.620 us; speedup vs baseline: 1.1500x; 1.0495x over previous
//
#include <hip/hip_runtime.h>
#include <math.h>

typedef short s16x8 __attribute__((ext_vector_type(8)));
typedef short s16x4 __attribute__((ext_vector_type(4)));
typedef float f32x4 __attribute__((ext_vector_type(4)));

#define MFMA(a, b, c)    __builtin_amdgcn_mfma_f32_16x16x32_bf16(a, b, c, 0, 0, 0)
#define MFMA16(a, b, c)  __builtin_amdgcn_mfma_f32_16x16x16bf16_1k(a, b, c, 0, 0, 0)

__device__ __forceinline__ float b2f(ushort u) {
    union { unsigned int i; float f; } v; v.i = ((unsigned int)u) << 16; return v.f;
}
__device__ __forceinline__ ushort f2b(float f) {
    union { float f; unsigned int i; } v; v.f = f;
    unsigned int r = v.i + 0x7fffu + ((v.i >> 16) & 1u);
    return (ushort)(r >> 16);
}
__device__ __forceinline__ float gelu_tanh(float v) {
    float u = 0.7978845608f * (v + 0.044715f * v * v * v);
    float e = __expf(-2.f * fabsf(u));
    float t = (1.f - e) / (1.f + e);            // tanh(|u|)
    t = (u < 0.f) ? -t : t;
    return 0.5f * v * (1.f + t);
}

// ---------------------------------------------------------------------------
// K0: all prep. blocks [0,192): qkv_w->wq; [192,256): proj_w->wp;
// [256,768): fc1/fc2->wf; [768,832): bias+mask table bm[cls][head][128][128].
// ---------------------------------------------------------------------------
__global__ __launch_bounds__(256) void k0_prep(
    const float* __restrict__ qkv_w, const float* __restrict__ proj_w,
    const float* __restrict__ fc1_w, const float* __restrict__ fc2_w,
    const float* __restrict__ rpb, ushort* __restrict__ wq,
    ushort* __restrict__ wp, ushort* __restrict__ wf, ushort* __restrict__ bm)
{
    int bid = blockIdx.x, tid = threadIdx.x;
    if (bid < 192) { int idx = bid * 256 + tid; wq[idx] = f2b(qkv_w[idx]); return; }
    if (bid < 256) { int idx = (bid - 192) * 256 + tid; wp[idx] = f2b(proj_w[idx]); return; }
    if (bid < 768) {
        int idx = (bid - 256) * 256 + tid;
        wf[idx] = f2b(idx < 65536 ? fc1_w[idx] : fc2_w[idx - 65536]);
        return;
    }
    int bi = bid - 768;                             // [0,64) = cls*8+head
    int cls = bi >> 3, head = bi & 7;
    int ed = (cls >> 2) & 1, eh = (cls >> 1) & 1, ew = cls & 1;
    int j = tid & 127;
    int tdj = j >> 6, thj = (j >> 3) & 7, twj = j & 7;
    int regj = (ed ? (tdj + 1) : 0) * 9
             + (eh ? ((thj < 4) ? 1 : 2) : 0) * 3
             + (ew ? ((twj < 4) ? 1 : 2) : 0);
    ushort* bmp = bm + (long)bi * 16384;
    for (int ii = 0; ii < 64; ++ii) {
        int i = (tid >> 7) * 64 + ii;
        int tdi = i >> 6, thi = (i >> 3) & 7, twi = i & 7;
        int regi = (ed ? (tdi + 1) : 0) * 9
                 + (eh ? ((thi < 4) ? 1 : 2) : 0) * 3
                 + (ew ? ((twi < 4) ? 1 : 2) : 0);
        int rpi = (tdi - tdj + 1) * 225 + (thi - thj + 7) * 15 + (twi - twj + 7);
        float v = rpb[rpi * 8 + head] + ((regi != regj) ? -100.f : 0.f);
        bmp[i * 128 + j] = f2b(v);
    }
}

// ---------------------------------------------------------------------------
// K23 (R6 merge): one block per WINDOW (512 x 256). Phase A: LN1 + shift +
// gather -> As (identical to old k2). Phase B: QKV GEMM; Q -> qb LDS,
// K -> kb LDS, V^T overwrites the dead As region (barrier before the
// overwrite, since all waves' MFMA reads of As must finish). Phase C: the
// R5-verified attention math, per wave 2 heads, ZERO barriers, q/k/v all
// LDS-local; only O (12.6MB) goes to HBM as [wi][head][tok][16].
// Eliminates the 50MB qkv HBM write + k3's ~63MB read + one kernel launch.
// LDS = 34816 (As/vt) + 33792 (qb) + 33792 (kb) = 100 KB (gfx950: <=160KB).
// ---------------------------------------------------------------------------
__global__ __launch_bounds__(256) void k23(
    const float* __restrict__ x, const float* __restrict__ g,
    const float* __restrict__ be, const ushort* __restrict__ wq,
    const float* __restrict__ qkv_b, const ushort* __restrict__ bm,
    ushort* __restrict__ obuf)
{
    __shared__ __align__(16) ushort As[128][136];   // LN1 out; later V^T [h][16][136]
    __shared__ __align__(16) ushort qb[128][132];   // Q [tok][128ch]
    __shared__ __align__(16) ushort kb[128][132];   // K [tok][128ch]
    int tid = threadIdx.x;
    int wi = blockIdx.x;
    int wd = (wi >> 6) & 3, wh = (wi >> 3) & 7, ww = wi & 7;
    int cls = ((wd == 3) << 2) | ((wh == 7) << 1) | (ww == 7);
    {   // Phase A: LN + shift + gather -> As (2 threads per row)
        int row = tid >> 1, half = tid & 1;
        int b = wi >> 8;
        int td = row >> 6, th = (row >> 3) & 7, tw = row & 7;
        int d = (wd * 2 + td + 1) & 7;
        int h = (wh * 8 + th + 4) & 63;
        int w = (ww * 8 + tw + 4) & 63;
        long src = (((long)((b * 8 + d) * 64 + h)) * 64 + w) * 128 + half * 64;
        float vals[64];
        float s = 0.f, q = 0.f;
        #pragma unroll
        for (int i = 0; i < 16; ++i) {
            float4 u = *(const float4*)&x[src + i * 4];
            vals[i * 4 + 0] = u.x; vals[i * 4 + 1] = u.y;
            vals[i * 4 + 2] = u.z; vals[i * 4 + 3] = u.w;
            s += u.x + u.y + u.z + u.w;
            q += u.x * u.x + u.y * u.y + u.z * u.z + u.w * u.w;
        }
        s += __shfl_xor(s, 1);
        q += __shfl_xor(q, 1);
        float mean = s * (1.f / 128.f);
        float rstd = rsqrtf(q * (1.f / 128.f) - mean * mean + 1e-5f);
        #pragma unroll
        for (int i = 0; i < 8; ++i) {
            ushort pk[8];
            #pragma unroll
            for (int jj = 0; jj < 8; ++jj) {
                int c = half * 64 + i * 8 + jj;
                pk[jj] = f2b((vals[i * 8 + jj] - mean) * rstd * g[c] + be[c]);
            }
            *(uint4*)&As[row][half * 64 + i * 8] = *(uint4*)pk;
        }
    }
    __syncthreads();
    int wv = tid >> 6, lane = tid & 63, li = lane & 15, quad = lane >> 4;
    int wm = wv >> 1, wn = wv & 1;
    // Phase B: QKV GEMM -> LDS (q->qb, k->kb, v^T->As region)
    for (int nb = 0; nb < 3; ++nb) {
        f32x4 acc[4][4] = {};
        for (int s = 0; s < 4; ++s) {
            s16x8 a[4], bw[4];
            #pragma unroll
            for (int mi = 0; mi < 4; ++mi)
                a[mi] = *(const s16x8*)&As[wm * 64 + mi * 16 + li][s * 32 + quad * 8];
            #pragma unroll
            for (int ni = 0; ni < 4; ++ni)
                bw[ni] = *(const s16x8*)&wq[(long)(nb * 128 + wn * 64 + ni * 16 + li) * 128
                                            + s * 32 + quad * 8];
            #pragma unroll
            for (int mi = 0; mi < 4; ++mi)
                #pragma unroll
                for (int ni = 0; ni < 4; ++ni)
                    acc[mi][ni] = MFMA(a[mi], bw[ni], acc[mi][ni]);
        }
        if (nb == 2) __syncthreads();   // all As (A-operand) reads done before V^T overwrite
        #pragma unroll
        for (int mi = 0; mi < 4; ++mi)
            #pragma unroll
            for (int ni = 0; ni < 4; ++ni) {
                int gcol = nb * 128 + wn * 64 + ni * 16 + li;
                float bias = qkv_b[gcol];
                float scale = (nb == 0) ? 0.25f : 1.f;   // SCALE = 16^-0.5
                #pragma unroll
                for (int r = 0; r < 4; ++r) {
                    int trow = wm * 64 + mi * 16 + quad * 4 + r;
                    ushort val = f2b((acc[mi][ni][r] + bias) * scale);
                    if (nb == 0) {
                        qb[trow][gcol] = val;
                    } else if (nb == 1) {
                        kb[trow][gcol - 128] = val;
                    } else {
                        int c2 = gcol - 256, hh = c2 >> 4, dd = c2 & 15;
                        ((ushort*)As)[hh * 2176 + dd * 136 + trow] = val;  // V^T [h][d][tok]
                    }
                }
            }
    }
    __syncthreads();
    // Phase C: attention (R5-verified math), wave wv -> heads 2wv, 2wv+1.
    const ushort* vtp = (const ushort*)As;
    for (int hh2 = 0; hh2 < 2; ++hh2) {
        int h = wv * 2 + hh2;
        long bmb = (long)(cls * 8 + h) * 16384;
        long ob = (long)wi * 16384 + h * 2048;
        for (int qq = 0; qq < 4; ++qq) {
            int row0 = qq * 32;
            s16x4 qf0 = *(const s16x4*)&qb[row0 + li][h * 16 + quad * 4];
            s16x4 qf1 = *(const s16x4*)&qb[row0 + 16 + li][h * 16 + quad * 4];
            float ps0 = 0.f, ps1 = 0.f;
            uint pa0[8][2], pa1[8][2];
            #pragma unroll
            for (int mi = 0; mi < 8; ++mi) {
                s16x4 kf = *(const s16x4*)&kb[mi * 16 + li][h * 16 + quad * 4];
                f32x4 z = {0.f, 0.f, 0.f, 0.f};
                f32x4 s0 = MFMA16(kf, qf0, z);
                f32x4 s1 = MFMA16(kf, qf1, z);
                s16x4 b0 = *(const s16x4*)&bm[bmb + (row0 + li) * 128 + mi * 16 + quad * 4];
                s16x4 b1 = *(const s16x4*)&bm[bmb + (row0 + 16 + li) * 128 + mi * 16 + quad * 4];
                float e0 = __expf(s0[0] + b2f((ushort)b0[0]));
                float e1 = __expf(s0[1] + b2f((ushort)b0[1]));
                float e2 = __expf(s0[2] + b2f((ushort)b0[2]));
                float e3 = __expf(s0[3] + b2f((ushort)b0[3]));
                ps0 += (e0 + e1) + (e2 + e3);
                pa0[mi][0] = (uint)f2b(e0) | ((uint)f2b(e1) << 16);
                pa0[mi][1] = (uint)f2b(e2) | ((uint)f2b(e3) << 16);
                float f0 = __expf(s1[0] + b2f((ushort)b1[0]));
                float f1 = __expf(s1[1] + b2f((ushort)b1[1]));
                float f2 = __expf(s1[2] + b2f((ushort)b1[2]));
                float f3 = __expf(s1[3] + b2f((ushort)b1[3]));
                ps1 += (f0 + f1) + (f2 + f3);
                pa1[mi][0] = (uint)f2b(f0) | ((uint)f2b(f1) << 16);
                pa1[mi][1] = (uint)f2b(f2) | ((uint)f2b(f3) << 16);
            }
            ps0 += __shfl_xor(ps0, 16); ps0 += __shfl_xor(ps0, 32);
            ps1 += __shfl_xor(ps1, 16); ps1 += __shfl_xor(ps1, 32);
            float inv0 = 1.f / ps0, inv1 = 1.f / ps1;
            f32x4 pc0 = {0.f, 0.f, 0.f, 0.f}, pc1 = {0.f, 0.f, 0.f, 0.f};
            #pragma unroll
            for (int mi = 0; mi < 8; ++mi) {
                s16x4 vf = *(const s16x4*)&vtp[h * 2176 + li * 136 + mi * 16 + quad * 4];
                union { uint2 u; s16x4 v; } a0, a1;
                a0.u.x = pa0[mi][0]; a0.u.y = pa0[mi][1];
                a1.u.x = pa1[mi][0]; a1.u.y = pa1[mi][1];
                pc0 = MFMA16(a0.v, vf, pc0);
                pc1 = MFMA16(a1.v, vf, pc1);
            }
            #pragma unroll
            for (int r = 0; r < 4; ++r) {
                float oi0 = __shfl(inv0, quad * 4 + r);
                float oi1 = __shfl(inv1, quad * 4 + r);
                int i0 = row0 + quad * 4 + r;
                int i1 = row0 + 16 + quad * 4 + r;
                obuf[ob + (long)i0 * 16 + li] = f2b(pc0[r] * oi0);
                obuf[ob + (long)i1 * 16 + li] = f2b(pc1[r] * oi1);
            }
        }
    }
}

// ---------------------------------------------------------------------------
// K45 (R6): unchanged R0-proven shape (103.4us): 64-token tile, 1024x256,
// x1 in x1t LDS (VGPR 96), LDS 52.7KB. Only aob stride changed: ao is now
// the compact O buffer [wi][head][tok][16], window stride 16384.
// ---------------------------------------------------------------------------
__global__ __launch_bounds__(256) void k45(
    const ushort* __restrict__ ao, const ushort* __restrict__ wp,
    const float* __restrict__ proj_b, const float* __restrict__ x,
    const float* __restrict__ g2, const float* __restrict__ be2,
    const ushort* __restrict__ wf1, const float* __restrict__ fc1_b,
    const ushort* __restrict__ wf2, const float* __restrict__ fc2_b,
    float* __restrict__ out)
{
    __shared__ __align__(16) ushort As[64][132];    // ao tile, later xs (LN2 out)
    __shared__ __align__(16) ushort x1t[64][132];   // x1 (bf16)
    __shared__ __align__(16) ushort hs[64][132];    // gelu(h) chunk
    __shared__ float redS[4][64];
    __shared__ float redQ[4][64];
    int tid = threadIdx.x;
    int b = blockIdx.x;
    int wi = b >> 1, half64 = b & 1;
    int wd = (wi >> 6) & 3, wh = (wi >> 3) & 7, ww = wi & 7;
    int bb = wi >> 8;
    long aob = (long)wi * 16384;
    int tok0 = half64 * 64;
    #pragma unroll
    for (int i = 0; i < 4; ++i) {
        int slot = tid + i * 256;               // 0..1023
        int row = slot & 63, hsl = slot >> 6;   // hsl = head*2 + (d-half)
        *(uint4*)&As[row][hsl * 8] =
            *(const uint4*)&ao[aob + (hsl >> 1) * 2048 + (long)(tok0 + row) * 16 + (hsl & 1) * 8];
    }
    __syncthreads();
    int wv = tid >> 6, lane = tid & 63, li = lane & 15, quad = lane >> 4;
    int wm = wv >> 1, wn = wv & 1;
    f32x4 acc[2][4] = {};
    for (int s = 0; s < 4; ++s) {
        s16x8 a[2], bw[4];
        #pragma unroll
        for (int mi = 0; mi < 2; ++mi)
            a[mi] = *(const s16x8*)&As[wm * 32 + mi * 16 + li][s * 32 + quad * 8];
        #pragma unroll
        for (int ni = 0; ni < 4; ++ni)
            bw[ni] = *(const s16x8*)&wp[(long)(wn * 64 + ni * 16 + li) * 128 + s * 32 + quad * 8];
        #pragma unroll
        for (int mi = 0; mi < 2; ++mi)
            #pragma unroll
            for (int ni = 0; ni < 4; ++ni)
                acc[mi][ni] = MFMA(a[mi], bw[ni], acc[mi][ni]);
    }
    // epilogue: residual add (f32 x) -> x1t (bf16)
    #pragma unroll
    for (int mi = 0; mi < 2; ++mi) {
        #pragma unroll
        for (int r = 0; r < 4; ++r) {
            int lrow = wm * 32 + mi * 16 + quad * 4 + r;
            int t = half64 * 64 + lrow;
            int td = t >> 6, th = (t >> 3) & 7, tw = t & 7;
            int d = (wd * 2 + td + 1) & 7, h = (wh * 8 + th + 4) & 63, w = (ww * 8 + tw + 4) & 63;
            long di = (((long)((bb * 8 + d) * 64 + h)) * 64 + w) * 128;
            #pragma unroll
            for (int ni = 0; ni < 4; ++ni) {
                int col = wn * 64 + ni * 16 + li;
                x1t[lrow][col] = f2b(acc[mi][ni][r] + proj_b[col] + x[di + col]);
            }
        }
    }
    __syncthreads();
    {   // LN2 from x1t -> xs (reuse As)
        int token = tid & 63, part = tid >> 6;
        float vals[32];
        float s = 0.f, q = 0.f;
        #pragma unroll
        for (int i = 0; i < 4; ++i) {
            uint4 u = *(const uint4*)&x1t[token][part * 32 + i * 8];
            const ushort* p = (const ushort*)&u;
            #pragma unroll
            for (int j = 0; j < 8; ++j) { float f = b2f(p[j]); vals[i * 8 + j] = f; s += f; q += f * f; }
        }
        redS[part][token] = s; redQ[part][token] = q;
        __syncthreads();
        float st = 0.f, qt = 0.f;
        #pragma unroll
        for (int p2 = 0; p2 < 4; ++p2) { st += redS[p2][token]; qt += redQ[p2][token]; }
        float mean = st * (1.f / 128.f);
        float rstd = rsqrtf(qt * (1.f / 128.f) - mean * mean + 1e-5f);
        #pragma unroll
        for (int i = 0; i < 4; ++i) {
            ushort packed[8];
            #pragma unroll
            for (int j = 0; j < 8; ++j) {
                int c = part * 32 + i * 8 + j;
                packed[j] = f2b((vals[i * 8 + j] - mean) * rstd * g2[c] + be2[c]);
            }
            *(uint4*)&As[token][part * 32 + i * 8] = *(uint4*)packed;
        }
    }
    __syncthreads();
    f32x4 yacc[2][4] = {};
    for (int hc = 0; hc < 4; ++hc) {
        f32x4 hacc[2][4] = {};
        #pragma unroll
        for (int kk = 0; kk < 4; ++kk) {
            s16x8 a[2], bw[4];
            #pragma unroll
            for (int mi = 0; mi < 2; ++mi)
                a[mi] = *(const s16x8*)&As[wm * 32 + mi * 16 + li][kk * 32 + quad * 8];
            #pragma unroll
            for (int ni = 0; ni < 4; ++ni)
                bw[ni] = *(const s16x8*)&wf1[(long)(hc * 128 + wn * 64 + ni * 16 + li) * 128
                                             + kk * 32 + quad * 8];
            #pragma unroll
            for (int mi = 0; mi < 2; ++mi)
                #pragma unroll
                for (int ni = 0; ni < 4; ++ni)
                    hacc[mi][ni] = MFMA(a[mi], bw[ni], hacc[mi][ni]);
        }
        #pragma unroll
        for (int mi = 0; mi < 2; ++mi)
            #pragma unroll
            for (int ni = 0; ni < 4; ++ni) {
                int col = wn * 64 + ni * 16 + li;
                float bbv = fc1_b[hc * 128 + col];
                #pragma unroll
                for (int r = 0; r < 4; ++r) {
                    int row = wm * 32 + mi * 16 + quad * 4 + r;
                    hs[row][col] = f2b(gelu_tanh(hacc[mi][ni][r] + bbv));
                }
            }
        __syncthreads();
        #pragma unroll
        for (int kk = 0; kk < 4; ++kk) {
            s16x8 a[2], bw[4];
            #pragma unroll
            for (int mi = 0; mi < 2; ++mi)
                a[mi] = *(const s16x8*)&hs[wm * 32 + mi * 16 + li][kk * 32 + quad * 8];
            #pragma unroll
            for (int ni = 0; ni < 4; ++ni)
                bw[ni] = *(const s16x8*)&wf2[(long)(wn * 64 + ni * 16 + li) * 512
                                             + hc * 128 + kk * 32 + quad * 8];
            #pragma unroll
            for (int mi = 0; mi < 2; ++mi)
                #pragma unroll
                for (int ni = 0; ni < 4; ++ni)
                    yacc[mi][ni] = MFMA(a[mi], bw[ni], yacc[mi][ni]);
        }
        __syncthreads();
    }
    #pragma unroll
    for (int mi = 0; mi < 2; ++mi) {
        #pragma unroll
        for (int r = 0; r < 4; ++r) {
            int lrow = wm * 32 + mi * 16 + quad * 4 + r;
            int t = half64 * 64 + lrow;
            int td = t >> 6, th = (t >> 3) & 7, tw = t & 7;
            int d = (wd * 2 + td + 1) & 7, h = (wh * 8 + th + 4) & 63, w = (ww * 8 + tw + 4) & 63;
            long di = (((long)((bb * 8 + d) * 64 + h)) * 64 + w) * 128;
            #pragma unroll
            for (int ni = 0; ni < 4; ++ni) {
                int col = wn * 64 + ni * 16 + li;
                out[di + col] = b2f(x1t[lrow][col]) + yacc[mi][ni][r] + fc2_b[col];
            }
        }
    }
}

// ---------------------------------------------------------------------------
// ws layout:
//   [0 .. 16.8MB): obuf = attn-out, [wi][head][tok][16] (window stride 16384).
//   tail (fixed offsets, unchanged): wq 96KB | wp 32KB | wf 256KB | bm 2MB.
// d_out holds ONLY the final f32 output (no scratch -> no races).
// ---------------------------------------------------------------------------
extern "C" void kernel_launch(void* const* d_in, const int* in_sizes, int n_in,
                              void* d_out, int out_size, void* d_ws, size_t ws_size,
                              hipStream_t stream)
{
    (void)in_sizes; (void)n_in; (void)out_size; (void)ws_size;
    const float* x      = (const float*)d_in[0];
    const float* qkv_w  = (const float*)d_in[1];
    const float* qkv_b  = (const float*)d_in[2];
    const float* proj_w = (const float*)d_in[3];
    const float* proj_b = (const float*)d_in[4];
    const float* rpb    = (const float*)d_in[5];
    const float* ln1_g  = (const float*)d_in[6];
    const float* ln1_b  = (const float*)d_in[7];
    const float* ln2_g  = (const float*)d_in[8];
    const float* ln2_b  = (const float*)d_in[9];
    const float* fc1_w  = (const float*)d_in[10];
    const float* fc1_b  = (const float*)d_in[11];
    const float* fc2_w  = (const float*)d_in[12];
    const float* fc2_b  = (const float*)d_in[13];
    float* out = (float*)d_out;

    ushort* obuf = (ushort*)d_ws;                       // 16.8 MB used
    ushort* wq   = (ushort*)((char*)d_ws + 50331648);   // 49152 elems
    ushort* wp   = wq + 49152;                          // 16384
    ushort* wf   = wp + 16384;                          // 131072
    ushort* bm   = wf + 131072;                         // 1048576

    hipLaunchKernelGGL(k0_prep, dim3(832), dim3(256), 0, stream,
                       qkv_w, proj_w, fc1_w, fc2_w, rpb, wq, wp, wf, bm);
    hipLaunchKernelGGL(k23, dim3(512), dim3(256), 0, stream,
                       x, ln1_g, ln1_b, wq, qkv_b, bm, obuf);
    hipLaunchKernelGGL(k45, dim3(1024), dim3(256), 0, stream,
                       obuf, wp, proj_b, x, ln2_g, ln2_b,
                       wf, fc1_b, wf + 65536, fc2_b, out);
}

// Round 7
// 267.204 us; speedup vs baseline: 1.1604x; 1.0090x over previous
//
#include <hip/hip_runtime.h>
#include <math.h>

typedef short s16x8 __attribute__((ext_vector_type(8)));
typedef short s16x4 __attribute__((ext_vector_type(4)));
typedef float f32x4 __attribute__((ext_vector_type(4)));

#define MFMA(a, b, c)    __builtin_amdgcn_mfma_f32_16x16x32_bf16(a, b, c, 0, 0, 0)
#define MFMA16(a, b, c)  __builtin_amdgcn_mfma_f32_16x16x16bf16_1k(a, b, c, 0, 0, 0)

__device__ __forceinline__ float b2f(ushort u) {
    union { unsigned int i; float f; } v; v.i = ((unsigned int)u) << 16; return v.f;
}
__device__ __forceinline__ ushort f2b(float f) {
    union { float f; unsigned int i; } v; v.f = f;
    unsigned int r = v.i + 0x7fffu + ((v.i >> 16) & 1u);
    return (ushort)(r >> 16);
}
__device__ __forceinline__ float gelu_tanh(float v) {
    float u = 0.7978845608f * (v + 0.044715f * v * v * v);
    float e = __expf(-2.f * fabsf(u));
    float t = (1.f - e) / (1.f + e);            // tanh(|u|)
    t = (u < 0.f) ? -t : t;
    return 0.5f * v * (1.f + t);
}

// ---------------------------------------------------------------------------
// K0: all prep. blocks [0,192): qkv_w->wq; [192,256): proj_w->wp;
// [256,768): fc1/fc2->wf; [768,832): bias+mask table bm[cls][head][128][128].
// ---------------------------------------------------------------------------
__global__ __launch_bounds__(256) void k0_prep(
    const float* __restrict__ qkv_w, const float* __restrict__ proj_w,
    const float* __restrict__ fc1_w, const float* __restrict__ fc2_w,
    const float* __restrict__ rpb, ushort* __restrict__ wq,
    ushort* __restrict__ wp, ushort* __restrict__ wf, ushort* __restrict__ bm)
{
    int bid = blockIdx.x, tid = threadIdx.x;
    if (bid < 192) { int idx = bid * 256 + tid; wq[idx] = f2b(qkv_w[idx]); return; }
    if (bid < 256) { int idx = (bid - 192) * 256 + tid; wp[idx] = f2b(proj_w[idx]); return; }
    if (bid < 768) {
        int idx = (bid - 256) * 256 + tid;
        wf[idx] = f2b(idx < 65536 ? fc1_w[idx] : fc2_w[idx - 65536]);
        return;
    }
    int bi = bid - 768;                             // [0,64) = cls*8+head
    int cls = bi >> 3, head = bi & 7;
    int ed = (cls >> 2) & 1, eh = (cls >> 1) & 1, ew = cls & 1;
    int j = tid & 127;
    int tdj = j >> 6, thj = (j >> 3) & 7, twj = j & 7;
    int regj = (ed ? (tdj + 1) : 0) * 9
             + (eh ? ((thj < 4) ? 1 : 2) : 0) * 3
             + (ew ? ((twj < 4) ? 1 : 2) : 0);
    ushort* bmp = bm + (long)bi * 16384;
    for (int ii = 0; ii < 64; ++ii) {
        int i = (tid >> 7) * 64 + ii;
        int tdi = i >> 6, thi = (i >> 3) & 7, twi = i & 7;
        int regi = (ed ? (tdi + 1) : 0) * 9
                 + (eh ? ((thi < 4) ? 1 : 2) : 0) * 3
                 + (ew ? ((twi < 4) ? 1 : 2) : 0);
        int rpi = (tdi - tdj + 1) * 225 + (thi - thj + 7) * 15 + (twi - twj + 7);
        float v = rpb[rpi * 8 + head] + ((regi != regj) ? -100.f : 0.f);
        bmp[i * 128 + j] = f2b(v);
    }
}

// ---------------------------------------------------------------------------
// K23 (R7: 512 threads = 8 waves; was 4). LDS unchanged (102.4KB -> 1
// block/CU), but waves/CU during residency doubles 4->8: phase C's serial
// exp/LDS chains now co-schedule 8 independent head-streams per CU.
// Phase A: LN1+shift+gather, 4 threads/row (vals[32], 2 shfl_xor).
// Phase B: QKV GEMM, 8 waves as 4m x 2n, acc[2][4], same epilogue/barriers.
// Phase C: ONE head per wave (was 2) - half the serial chain per wave.
// Math per phase identical to R6 (verified, absmax 0.03125).
// ---------------------------------------------------------------------------
__global__ __launch_bounds__(512) void k23(
    const float* __restrict__ x, const float* __restrict__ g,
    const float* __restrict__ be, const ushort* __restrict__ wq,
    const float* __restrict__ qkv_b, const ushort* __restrict__ bm,
    ushort* __restrict__ obuf)
{
    __shared__ __align__(16) ushort As[128][136];   // LN1 out; later V^T [h][16][136]
    __shared__ __align__(16) ushort qb[128][132];   // Q [tok][128ch]
    __shared__ __align__(16) ushort kb[128][132];   // K [tok][128ch]
    int tid = threadIdx.x;
    int wi = blockIdx.x;
    int wd = (wi >> 6) & 3, wh = (wi >> 3) & 7, ww = wi & 7;
    int cls = ((wd == 3) << 2) | ((wh == 7) << 1) | (ww == 7);
    {   // Phase A: LN + shift + gather -> As (4 threads per row)
        int row = tid >> 2, part = tid & 3;
        int b = wi >> 8;
        int td = row >> 6, th = (row >> 3) & 7, tw = row & 7;
        int d = (wd * 2 + td + 1) & 7;
        int h = (wh * 8 + th + 4) & 63;
        int w = (ww * 8 + tw + 4) & 63;
        long src = (((long)((b * 8 + d) * 64 + h)) * 64 + w) * 128 + part * 32;
        float vals[32];
        float s = 0.f, q = 0.f;
        #pragma unroll
        for (int i = 0; i < 8; ++i) {
            float4 u = *(const float4*)&x[src + i * 4];
            vals[i * 4 + 0] = u.x; vals[i * 4 + 1] = u.y;
            vals[i * 4 + 2] = u.z; vals[i * 4 + 3] = u.w;
            s += u.x + u.y + u.z + u.w;
            q += u.x * u.x + u.y * u.y + u.z * u.z + u.w * u.w;
        }
        s += __shfl_xor(s, 1); s += __shfl_xor(s, 2);
        q += __shfl_xor(q, 1); q += __shfl_xor(q, 2);
        float mean = s * (1.f / 128.f);
        float rstd = rsqrtf(q * (1.f / 128.f) - mean * mean + 1e-5f);
        #pragma unroll
        for (int i = 0; i < 4; ++i) {
            ushort pk[8];
            #pragma unroll
            for (int jj = 0; jj < 8; ++jj) {
                int c = part * 32 + i * 8 + jj;
                pk[jj] = f2b((vals[i * 8 + jj] - mean) * rstd * g[c] + be[c]);
            }
            *(uint4*)&As[row][part * 32 + i * 8] = *(uint4*)pk;
        }
    }
    __syncthreads();
    int wv = tid >> 6, lane = tid & 63, li = lane & 15, quad = lane >> 4;
    int wm = wv >> 1, wn = wv & 1;                  // wm 0..3, wn 0..1
    // Phase B: QKV GEMM -> LDS (q->qb, k->kb, v^T->As region)
    for (int nb = 0; nb < 3; ++nb) {
        f32x4 acc[2][4] = {};
        for (int s = 0; s < 4; ++s) {
            s16x8 a[2], bw[4];
            #pragma unroll
            for (int mi = 0; mi < 2; ++mi)
                a[mi] = *(const s16x8*)&As[wm * 32 + mi * 16 + li][s * 32 + quad * 8];
            #pragma unroll
            for (int ni = 0; ni < 4; ++ni)
                bw[ni] = *(const s16x8*)&wq[(long)(nb * 128 + wn * 64 + ni * 16 + li) * 128
                                            + s * 32 + quad * 8];
            #pragma unroll
            for (int mi = 0; mi < 2; ++mi)
                #pragma unroll
                for (int ni = 0; ni < 4; ++ni)
                    acc[mi][ni] = MFMA(a[mi], bw[ni], acc[mi][ni]);
        }
        if (nb == 2) __syncthreads();   // all As (A-operand) reads done before V^T overwrite
        #pragma unroll
        for (int mi = 0; mi < 2; ++mi)
            #pragma unroll
            for (int ni = 0; ni < 4; ++ni) {
                int gcol = nb * 128 + wn * 64 + ni * 16 + li;
                float bias = qkv_b[gcol];
                float scale = (nb == 0) ? 0.25f : 1.f;   // SCALE = 16^-0.5
                #pragma unroll
                for (int r = 0; r < 4; ++r) {
                    int trow = wm * 32 + mi * 16 + quad * 4 + r;
                    ushort val = f2b((acc[mi][ni][r] + bias) * scale);
                    if (nb == 0) {
                        qb[trow][gcol] = val;
                    } else if (nb == 1) {
                        kb[trow][gcol - 128] = val;
                    } else {
                        int c2 = gcol - 256, hh = c2 >> 4, dd = c2 & 15;
                        ((ushort*)As)[hh * 2176 + dd * 136 + trow] = val;  // V^T [h][d][tok]
                    }
                }
            }
    }
    __syncthreads();
    // Phase C: attention (R5-verified math), wave wv = head wv.
    const ushort* vtp = (const ushort*)As;
    {
        int h = wv;
        long bmb = (long)(cls * 8 + h) * 16384;
        long ob = (long)wi * 16384 + h * 2048;
        for (int qq = 0; qq < 4; ++qq) {
            int row0 = qq * 32;
            s16x4 qf0 = *(const s16x4*)&qb[row0 + li][h * 16 + quad * 4];
            s16x4 qf1 = *(const s16x4*)&qb[row0 + 16 + li][h * 16 + quad * 4];
            float ps0 = 0.f, ps1 = 0.f;
            uint pa0[8][2], pa1[8][2];
            #pragma unroll
            for (int mi = 0; mi < 8; ++mi) {
                s16x4 kf = *(const s16x4*)&kb[mi * 16 + li][h * 16 + quad * 4];
                f32x4 z = {0.f, 0.f, 0.f, 0.f};
                f32x4 s0 = MFMA16(kf, qf0, z);
                f32x4 s1 = MFMA16(kf, qf1, z);
                s16x4 b0 = *(const s16x4*)&bm[bmb + (row0 + li) * 128 + mi * 16 + quad * 4];
                s16x4 b1 = *(const s16x4*)&bm[bmb + (row0 + 16 + li) * 128 + mi * 16 + quad * 4];
                float e0 = __expf(s0[0] + b2f((ushort)b0[0]));
                float e1 = __expf(s0[1] + b2f((ushort)b0[1]));
                float e2 = __expf(s0[2] + b2f((ushort)b0[2]));
                float e3 = __expf(s0[3] + b2f((ushort)b0[3]));
                ps0 += (e0 + e1) + (e2 + e3);
                pa0[mi][0] = (uint)f2b(e0) | ((uint)f2b(e1) << 16);
                pa0[mi][1] = (uint)f2b(e2) | ((uint)f2b(e3) << 16);
                float f0 = __expf(s1[0] + b2f((ushort)b1[0]));
                float f1 = __expf(s1[1] + b2f((ushort)b1[1]));
                float f2 = __expf(s1[2] + b2f((ushort)b1[2]));
                float f3 = __expf(s1[3] + b2f((ushort)b1[3]));
                ps1 += (f0 + f1) + (f2 + f3);
                pa1[mi][0] = (uint)f2b(f0) | ((uint)f2b(f1) << 16);
                pa1[mi][1] = (uint)f2b(f2) | ((uint)f2b(f3) << 16);
            }
            ps0 += __shfl_xor(ps0, 16); ps0 += __shfl_xor(ps0, 32);
            ps1 += __shfl_xor(ps1, 16); ps1 += __shfl_xor(ps1, 32);
            float inv0 = 1.f / ps0, inv1 = 1.f / ps1;
            f32x4 pc0 = {0.f, 0.f, 0.f, 0.f}, pc1 = {0.f, 0.f, 0.f, 0.f};
            #pragma unroll
            for (int mi = 0; mi < 8; ++mi) {
                s16x4 vf = *(const s16x4*)&vtp[h * 2176 + li * 136 + mi * 16 + quad * 4];
                union { uint2 u; s16x4 v; } a0, a1;
                a0.u.x = pa0[mi][0]; a0.u.y = pa0[mi][1];
                a1.u.x = pa1[mi][0]; a1.u.y = pa1[mi][1];
                pc0 = MFMA16(a0.v, vf, pc0);
                pc1 = MFMA16(a1.v, vf, pc1);
            }
            #pragma unroll
            for (int r = 0; r < 4; ++r) {
                float oi0 = __shfl(inv0, quad * 4 + r);
                float oi1 = __shfl(inv1, quad * 4 + r);
                int i0 = row0 + quad * 4 + r;
                int i1 = row0 + 16 + quad * 4 + r;
                obuf[ob + (long)i0 * 16 + li] = f2b(pc0[r] * oi0);
                obuf[ob + (long)i1 * 16 + li] = f2b(pc1[r] * oi1);
            }
        }
    }
}

// ---------------------------------------------------------------------------
// K45 (R7): unchanged R0-proven shape (103.4us measured): 64-token tile,
// 1024x256, x1 in x1t LDS (VGPR 96), LDS 52.7KB. ao = compact O buffer
// [wi][head][tok][16], window stride 16384.
// ---------------------------------------------------------------------------
__global__ __launch_bounds__(256) void k45(
    const ushort* __restrict__ ao, const ushort* __restrict__ wp,
    const float* __restrict__ proj_b, const float* __restrict__ x,
    const float* __restrict__ g2, const float* __restrict__ be2,
    const ushort* __restrict__ wf1, const float* __restrict__ fc1_b,
    const ushort* __restrict__ wf2, const float* __restrict__ fc2_b,
    float* __restrict__ out)
{
    __shared__ __align__(16) ushort As[64][132];    // ao tile, later xs (LN2 out)
    __shared__ __align__(16) ushort x1t[64][132];   // x1 (bf16)
    __shared__ __align__(16) ushort hs[64][132];    // gelu(h) chunk
    __shared__ float redS[4][64];
    __shared__ float redQ[4][64];
    int tid = threadIdx.x;
    int b = blockIdx.x;
    int wi = b >> 1, half64 = b & 1;
    int wd = (wi >> 6) & 3, wh = (wi >> 3) & 7, ww = wi & 7;
    int bb = wi >> 8;
    long aob = (long)wi * 16384;
    int tok0 = half64 * 64;
    #pragma unroll
    for (int i = 0; i < 4; ++i) {
        int slot = tid + i * 256;               // 0..1023
        int row = slot & 63, hsl = slot >> 6;   // hsl = head*2 + (d-half)
        *(uint4*)&As[row][hsl * 8] =
            *(const uint4*)&ao[aob + (hsl >> 1) * 2048 + (long)(tok0 + row) * 16 + (hsl & 1) * 8];
    }
    __syncthreads();
    int wv = tid >> 6, lane = tid & 63, li = lane & 15, quad = lane >> 4;
    int wm = wv >> 1, wn = wv & 1;
    f32x4 acc[2][4] = {};
    for (int s = 0; s < 4; ++s) {
        s16x8 a[2], bw[4];
        #pragma unroll
        for (int mi = 0; mi < 2; ++mi)
            a[mi] = *(const s16x8*)&As[wm * 32 + mi * 16 + li][s * 32 + quad * 8];
        #pragma unroll
        for (int ni = 0; ni < 4; ++ni)
            bw[ni] = *(const s16x8*)&wp[(long)(wn * 64 + ni * 16 + li) * 128 + s * 32 + quad * 8];
        #pragma unroll
        for (int mi = 0; mi < 2; ++mi)
            #pragma unroll
            for (int ni = 0; ni < 4; ++ni)
                acc[mi][ni] = MFMA(a[mi], bw[ni], acc[mi][ni]);
    }
    // epilogue: residual add (f32 x) -> x1t (bf16)
    #pragma unroll
    for (int mi = 0; mi < 2; ++mi) {
        #pragma unroll
        for (int r = 0; r < 4; ++r) {
            int lrow = wm * 32 + mi * 16 + quad * 4 + r;
            int t = half64 * 64 + lrow;
            int td = t >> 6, th = (t >> 3) & 7, tw = t & 7;
            int d = (wd * 2 + td + 1) & 7, h = (wh * 8 + th + 4) & 63, w = (ww * 8 + tw + 4) & 63;
            long di = (((long)((bb * 8 + d) * 64 + h)) * 64 + w) * 128;
            #pragma unroll
            for (int ni = 0; ni < 4; ++ni) {
                int col = wn * 64 + ni * 16 + li;
                x1t[lrow][col] = f2b(acc[mi][ni][r] + proj_b[col] + x[di + col]);
            }
        }
    }
    __syncthreads();
    {   // LN2 from x1t -> xs (reuse As)
        int token = tid & 63, part = tid >> 6;
        float vals[32];
        float s = 0.f, q = 0.f;
        #pragma unroll
        for (int i = 0; i < 4; ++i) {
            uint4 u = *(const uint4*)&x1t[token][part * 32 + i * 8];
            const ushort* p = (const ushort*)&u;
            #pragma unroll
            for (int j = 0; j < 8; ++j) { float f = b2f(p[j]); vals[i * 8 + j] = f; s += f; q += f * f; }
        }
        redS[part][token] = s; redQ[part][token] = q;
        __syncthreads();
        float st = 0.f, qt = 0.f;
        #pragma unroll
        for (int p2 = 0; p2 < 4; ++p2) { st += redS[p2][token]; qt += redQ[p2][token]; }
        float mean = st * (1.f / 128.f);
        float rstd = rsqrtf(qt * (1.f / 128.f) - mean * mean + 1e-5f);
        #pragma unroll
        for (int i = 0; i < 4; ++i) {
            ushort packed[8];
            #pragma unroll
            for (int j = 0; j < 8; ++j) {
                int c = part * 32 + i * 8 + j;
                packed[j] = f2b((vals[i * 8 + j] - mean) * rstd * g2[c] + be2[c]);
            }
            *(uint4*)&As[token][part * 32 + i * 8] = *(uint4*)packed;
        }
    }
    __syncthreads();
    f32x4 yacc[2][4] = {};
    for (int hc = 0; hc < 4; ++hc) {
        f32x4 hacc[2][4] = {};
        #pragma unroll
        for (int kk = 0; kk < 4; ++kk) {
            s16x8 a[2], bw[4];
            #pragma unroll
            for (int mi = 0; mi < 2; ++mi)
                a[mi] = *(const s16x8*)&As[wm * 32 + mi * 16 + li][kk * 32 + quad * 8];
            #pragma unroll
            for (int ni = 0; ni < 4; ++ni)
                bw[ni] = *(const s16x8*)&wf1[(long)(hc * 128 + wn * 64 + ni * 16 + li) * 128
                                             + kk * 32 + quad * 8];
            #pragma unroll
            for (int mi = 0; mi < 2; ++mi)
                #pragma unroll
                for (int ni = 0; ni < 4; ++ni)
                    hacc[mi][ni] = MFMA(a[mi], bw[ni], hacc[mi][ni]);
        }
        #pragma unroll
        for (int mi = 0; mi < 2; ++mi)
            #pragma unroll
            for (int ni = 0; ni < 4; ++ni) {
                int col = wn * 64 + ni * 16 + li;
                float bbv = fc1_b[hc * 128 + col];
                #pragma unroll
                for (int r = 0; r < 4; ++r) {
                    int row = wm * 32 + mi * 16 + quad * 4 + r;
                    hs[row][col] = f2b(gelu_tanh(hacc[mi][ni][r] + bbv));
                }
            }
        __syncthreads();
        #pragma unroll
        for (int kk = 0; kk < 4; ++kk) {
            s16x8 a[2], bw[4];
            #pragma unroll
            for (int mi = 0; mi < 2; ++mi)
                a[mi] = *(const s16x8*)&hs[wm * 32 + mi * 16 + li][kk * 32 + quad * 8];
            #pragma unroll
            for (int ni = 0; ni < 4; ++ni)
                bw[ni] = *(const s16x8*)&wf2[(long)(wn * 64 + ni * 16 + li) * 512
                                             + hc * 128 + kk * 32 + quad * 8];
            #pragma unroll
            for (int mi = 0; mi < 2; ++mi)
                #pragma unroll
                for (int ni = 0; ni < 4; ++ni)
                    yacc[mi][ni] = MFMA(a[mi], bw[ni], yacc[mi][ni]);
        }
        __syncthreads();
    }
    #pragma unroll
    for (int mi = 0; mi < 2; ++mi) {
        #pragma unroll
        for (int r = 0; r < 4; ++r) {
            int lrow = wm * 32 + mi * 16 + quad * 4 + r;
            int t = half64 * 64 + lrow;
            int td = t >> 6, th = (t >> 3) & 7, tw = t & 7;
            int d = (wd * 2 + td + 1) & 7, h = (wh * 8 + th + 4) & 63, w = (ww * 8 + tw + 4) & 63;
            long di = (((long)((bb * 8 + d) * 64 + h)) * 64 + w) * 128;
            #pragma unroll
            for (int ni = 0; ni < 4; ++ni) {
                int col = wn * 64 + ni * 16 + li;
                out[di + col] = b2f(x1t[lrow][col]) + yacc[mi][ni][r] + fc2_b[col];
            }
        }
    }
}

// ---------------------------------------------------------------------------
// ws layout:
//   [0 .. 16.8MB): obuf = attn-out, [wi][head][tok][16] (window stride 16384).
//   tail (fixed offsets, unchanged): wq 96KB | wp 32KB | wf 256KB | bm 2MB.
// d_out holds ONLY the final f32 output (no scratch -> no races).
// ---------------------------------------------------------------------------
extern "C" void kernel_launch(void* const* d_in, const int* in_sizes, int n_in,
                              void* d_out, int out_size, void* d_ws, size_t ws_size,
                              hipStream_t stream)
{
    (void)in_sizes; (void)n_in; (void)out_size; (void)ws_size;
    const float* x      = (const float*)d_in[0];
    const float* qkv_w  = (const float*)d_in[1];
    const float* qkv_b  = (const float*)d_in[2];
    const float* proj_w = (const float*)d_in[3];
    const float* proj_b = (const float*)d_in[4];
    const float* rpb    = (const float*)d_in[5];
    const float* ln1_g  = (const float*)d_in[6];
    const float* ln1_b  = (const float*)d_in[7];
    const float* ln2_g  = (const float*)d_in[8];
    const float* ln2_b  = (const float*)d_in[9];
    const float* fc1_w  = (const float*)d_in[10];
    const float* fc1_b  = (const float*)d_in[11];
    const float* fc2_w  = (const float*)d_in[12];
    const float* fc2_b  = (const float*)d_in[13];
    float* out = (float*)d_out;

    ushort* obuf = (ushort*)d_ws;                       // 16.8 MB used
    ushort* wq   = (ushort*)((char*)d_ws + 50331648);   // 49152 elems
    ushort* wp   = wq + 49152;                          // 16384
    ushort* wf   = wp + 16384;                          // 131072
    ushort* bm   = wf + 131072;                         // 1048576

    hipLaunchKernelGGL(k0_prep, dim3(832), dim3(256), 0, stream,
                       qkv_w, proj_w, fc1_w, fc2_w, rpb, wq, wp, wf, bm);
    hipLaunchKernelGGL(k23, dim3(512), dim3(512), 0, stream,
                       x, ln1_g, ln1_b, wq, qkv_b, bm, obuf);
    hipLaunchKernelGGL(k45, dim3(1024), dim3(256), 0, stream,
                       obuf, wp, proj_b, x, ln2_g, ln2_b,
                       wf, fc1_b, wf + 65536, fc2_b, out);
}